// Round 11
// baseline (110.585 us; speedup 1.0000x reference)
//
#include <hip/hip_runtime.h>

// SSKernelNPLR, 2-kernel pipeline. H=256, N=32 (M=64 conj-extended), R=1, L=8192.
// K1 ssk_S (grid 1024, 512 thr, VGPR<=64 via launch_bounds(512,8)): contour with
//    8-lane node groups. Lane l of a group owns 4 state-pairs (m = (l&7)*4+k),
//    params streamed from LDS. Per node j: 4 G-folds -> regs + local (a,b);
//    3-level shfl_xor(1,2,4) group reduce -> (a_j,b_j); q_j = z a/(1+b);
//    S_m += q-fold into 8 VGPRs. 16 node-iters/thread (1024 nodes/block,
//    4 blocks/h). Reduce: masked butterfly (xor 8,16,32) -> LDS -> 64-thread
//    cross-wave sum -> Sws [h][part][2m+bit].
// K2 ssk_B (grid 256, 1024 thr): per-head algebra redo + combine 4 S partials +
//    z=-1 node -> C~ -> v-vectors; Cauchy at z_j = 2i tan(pi j/L) + Woodbury
//    + (1+iT); real-irfft packing; 6-stage radix-4 Stockham inverse FFT -> out.

#define HH 256
#define NN 32
#define MF 4096

typedef float2 c32;

__device__ __forceinline__ c32 cmul(c32 a, c32 b){ return make_float2(a.x*b.x - a.y*b.y, a.x*b.y + a.y*b.x); }
__device__ __forceinline__ c32 cadd(c32 a, c32 b){ return make_float2(a.x+b.x, a.y+b.y); }
__device__ __forceinline__ c32 csub(c32 a, c32 b){ return make_float2(a.x-b.x, a.y-b.y); }
__device__ __forceinline__ c32 cconjf(c32 a){ return make_float2(a.x, -a.y); }
__device__ __forceinline__ float frcp(float x){ return __builtin_amdgcn_rcpf(x); }

// ---------------- K1: register-fused contour (8-lane node groups) ----------
__global__ __launch_bounds__(512, 8)
void ssk_S(const float* __restrict__ log_dt, const float* __restrict__ invwr,
           const float* __restrict__ wim, const float* __restrict__ Pin,
           const float* __restrict__ Cin, float* __restrict__ Sws)
{
  __shared__ __align__(16) float4 ta_s[32];   // (d.x, d.y, pc.x, pc.y)
  __shared__ c32 pu_s[32];
  __shared__ float red[8*64];                 // [wave][component]
  const int bid = blockIdx.x;
  const int h = bid >> 2;
  const int base = (bid & 3) << 10;           // 0,1024,2048,3072
  const int tid = threadIdx.x;

  // ---- A1: per-head algebra (wave 0; m = tid, conj half for m>=32) ----
  if (tid < 64) {
    const int n = tid & 31;
    const bool cj = tid >= 32;
    const float dt = expf(log_dt[h]);
    float wr = -expf(invwr[h*NN + n]);
    float wi = wim[h*NN + n];
    if (cj) wi = -wi;
    const float tdt = 2.0f / dt;
    float dr = tdt - wr, di = -wi;
    float invd = 1.0f / (dr*dr + di*di);
    c32 D = make_float2(dr*invd, -di*invd);   // 1/(2/dt - w)
    c32 E = make_float2(tdt + wr, wi);        // 2/dt + w
    c32 Pf = make_float2(Pin[(h*NN+n)*2], Pin[(h*NN+n)*2+1]);
    if (cj) Pf.y = -Pf.y;
    c32 Cf = make_float2(Cin[(h*NN+n)*2], Cin[(h*NN+n)*2+1]);
    if (cj) Cf.y = -Cf.y;
    float rm = (Pf.x*Pf.x + Pf.y*Pf.y) * D.x; // Rm = 1 + sum |Pf|^2 Re(D)
    #pragma unroll
    for (int off = 32; off >= 1; off >>= 1) rm += __shfl_xor(rm, off, 64);
    rm += 1.0f;
    c32 Rc = cmul(cconjf(Pf), D);
    float invrm = 1.0f / rm;
    Rc.x *= invrm; Rc.y *= invrm;
    c32 RP = cmul(Rc, Pf);
    #pragma unroll
    for (int off = 32; off >= 1; off >>= 1) {
      RP.x += __shfl_xor(RP.x, off, 64);
      RP.y += __shfl_xor(RP.y, off, 64);
    }
    c32 Q2 = cconjf(Pf);
    c32 s  = csub(cmul(Rc, E), cmul(RP, Q2));
    c32 u  = cadd(Q2, s);                     // dA = diag(dd) - pp u^T
    c32 dd = cmul(D, E);
    c32 pp = cmul(D, Pf);
    c32 pc = cmul(pp, Cf);
    c32 pu = cmul(pp, u);
    if (tid < 32) {
      ta_s[tid] = make_float4(dd.x, dd.y, pc.x, pc.y);
      pu_s[tid] = pu;
    }
  }
  __syncthreads();

  const int sub = tid & 7;                    // 4-state slice
  const int grp = tid >> 3;                   // node slot 0..63

  float ssx[4], ssy[4];
  #pragma unroll
  for (int k = 0; k < 4; k++) { ssx[k] = 0.0f; ssy[k] = 0.0f; }

  for (int it = 0; it < 16; it++) {
    const int j = base + (it << 6) + grp;     // node index 0..4095
    float rev = (float)j * (1.0f/8192.0f);
    float zx = __builtin_amdgcn_cosf(rev);
    float zy = __builtin_amdgcn_sinf(rev);

    float fsx[4], fsy[4], fdx[4], fdy[4];
    float ax = 0.0f, ay = 0.0f, bx = 0.0f, by = 0.0f;
    #pragma unroll
    for (int k = 0; k < 4; k++) {
      float4 ta = ta_s[sub*4 + k];            // LDS-streamed params
      c32 pu = pu_s[sub*4 + k];
      float dxx = zx - ta.x;
      float dy1 = zy - ta.y;
      float dy2 = zy + ta.y;
      float xx  = dxx*dxx;
      float n1  = fmaf(dy1, dy1, xx);
      float n2  = fmaf(dy2, dy2, xx);
      float ip  = frcp(n1*n2);
      float i1  = n2*ip, i2 = n1*ip;
      float glx = dxx*i1, gly = -dy1*i1;      // 1/(z - d)
      float ghx = dxx*i2, ghy = -dy2*i2;      // 1/(z - conj d)
      float sx = glx + ghx, sy = gly + ghy;
      float dxg = glx - ghx, dyg = gly - ghy;
      fsx[k] = sx; fsy[k] = sy; fdx[k] = dxg; fdy[k] = dyg;
      ax = fmaf(ta.z, sx, fmaf(-ta.w, dyg, ax));
      ay = fmaf(ta.z, sy, fmaf( ta.w, dxg, ay));
      bx = fmaf(pu.x, sx, fmaf(-pu.y, dyg, bx));
      by = fmaf(pu.x, sy, fmaf( pu.y, dxg, by));
    }
    // 8-lane group reduce: lanes hold disjoint state slices
    ax += __shfl_xor(ax, 1, 64); ax += __shfl_xor(ax, 2, 64); ax += __shfl_xor(ax, 4, 64);
    ay += __shfl_xor(ay, 1, 64); ay += __shfl_xor(ay, 2, 64); ay += __shfl_xor(ay, 4, 64);
    bx += __shfl_xor(bx, 1, 64); bx += __shfl_xor(bx, 2, 64); bx += __shfl_xor(bx, 4, 64);
    by += __shfl_xor(by, 1, 64); by += __shfl_xor(by, 2, 64); by += __shfl_xor(by, 4, 64);
    // q = z a/(1+b)  (group-redundant)
    float denx = 1.0f + bx, deny = by;
    float idn = frcp(fmaf(denx, denx, deny*deny));
    float tx = (ax*denx + ay*deny)*idn;
    float ty = (ay*denx - ax*deny)*idn;
    float qx = zx*tx - zy*ty;
    float qy = zx*ty + zy*tx;
    if (j == 0) { qx *= 0.5f; qy *= 0.5f; }   // self-conj node z=1
    #pragma unroll
    for (int k = 0; k < 4; k++) {
      ssx[k] = fmaf(qx, fsx[k], fmaf(-qy, fsy[k], ssx[k]));
      ssy[k] = fmaf(qx, fdy[k], fmaf( qy, fdx[k], ssy[k]));
    }
  }

  // ---- masked wave butterfly: combine lanes with the same sub ----
  #pragma unroll
  for (int off = 8; off <= 32; off <<= 1) {
    #pragma unroll
    for (int k = 0; k < 4; k++) {
      ssx[k] += __shfl_xor(ssx[k], off, 64);
      ssy[k] += __shfl_xor(ssy[k], off, 64);
    }
  }
  const int lane = tid & 63;
  const int wv = tid >> 6;
  if (lane < 8) {   // sub == lane for these lanes
    #pragma unroll
    for (int k = 0; k < 4; k++) {
      red[wv*64 + lane*8 + 2*k]     = ssx[k];   // component c = 2m+bit, m=lane*4+k
      red[wv*64 + lane*8 + 2*k + 1] = ssy[k];
    }
  }
  __syncthreads();

  if (tid < 64) {
    float t = 0.0f;
    #pragma unroll
    for (int w = 0; w < 8; w++) t += red[w*64 + tid];
    Sws[bid*64 + tid] = t;    // layout: [h][part][2m+bit]
  }
}

// ---------------- K2: combine + Cauchy/Woodbury + irfft (r9, verified) -----
__global__ __launch_bounds__(1024, 4)
void ssk_B(const float* __restrict__ log_dt, const float* __restrict__ invwr,
           const float* __restrict__ wim, const float* __restrict__ Pin,
           const float* __restrict__ Bin, const float* __restrict__ Cin,
           const float* __restrict__ Sws, c32* __restrict__ out)
{
  __shared__ __align__(16) c32 Xs[4098];   // spectrum / FFT ping
  __shared__ __align__(16) c32 Zs[4096];   // packed seq / FFT pong
  __shared__ c32 wdt_s[NN];
  __shared__ c32 vs[4][NN];
  const int h = blockIdx.x;
  const int tid = threadIdx.x;

  // ---- per-head algebra redo + combine (wave 0) ----
  if (tid < 64) {
    const int n = tid & 31;
    const bool cj = tid >= 32;
    const float dt = expf(log_dt[h]);
    float wr = -expf(invwr[h*NN + n]);
    float wi = wim[h*NN + n];
    if (cj) wi = -wi;
    const float tdt = 2.0f / dt;
    float dr = tdt - wr, di = -wi;
    float invd = 1.0f / (dr*dr + di*di);
    c32 D = make_float2(dr*invd, -di*invd);
    c32 E = make_float2(tdt + wr, wi);
    c32 Pf = make_float2(Pin[(h*NN+n)*2], Pin[(h*NN+n)*2+1]);
    if (cj) Pf.y = -Pf.y;
    c32 Cf = make_float2(Cin[(h*NN+n)*2], Cin[(h*NN+n)*2+1]);
    if (cj) Cf.y = -Cf.y;
    float rm = (Pf.x*Pf.x + Pf.y*Pf.y) * D.x;
    #pragma unroll
    for (int off = 32; off >= 1; off >>= 1) rm += __shfl_xor(rm, off, 64);
    rm += 1.0f;
    c32 Rc = cmul(cconjf(Pf), D);
    float invrm = 1.0f / rm;
    Rc.x *= invrm; Rc.y *= invrm;
    c32 RP = cmul(Rc, Pf);
    #pragma unroll
    for (int off = 32; off >= 1; off >>= 1) {
      RP.x += __shfl_xor(RP.x, off, 64);
      RP.y += __shfl_xor(RP.y, off, 64);
    }
    c32 Q2 = cconjf(Pf);
    c32 s  = csub(cmul(Rc, E), cmul(RP, Q2));
    c32 u  = cadd(Q2, s);
    c32 dd = cmul(D, E);
    c32 pp = cmul(D, Pf);
    c32 pc = cmul(pp, Cf);
    c32 pu = cmul(pp, u);

    // z = -1 node: g = conj(-1-d)/|.|^2 ; a,b real (conj-pair fold)
    float dxxn = -1.0f - dd.x;
    float nn1 = fmaf(dxxn, dxxn, dd.y*dd.y);
    float ii = frcp(nn1);
    float glxn = dxxn*ii, glyn = dd.y*ii;
    float aterm = 2.0f*(pc.x*glxn - pc.y*glyn);
    float bterm = 2.0f*(pu.x*glxn - pu.y*glyn);
    #pragma unroll
    for (int off = 16; off >= 1; off >>= 1) {
      aterm += __shfl_xor(aterm, off, 64);
      bterm += __shfl_xor(bterm, off, 64);
    }

    if (tid < 32) {
      const int m = tid;
      // exact diagonal part d^8192
      c32 dL = dd;
      #pragma unroll
      for (int i2 = 0; i2 < 13; i2++) dL = cmul(dL, dL);
      // total S: 4 partials + z=-1 node (q real, half weight)
      c32 S;
      S.x = (Sws[h*256 + 2*m]       + Sws[h*256 + 64 + 2*m])
          + (Sws[h*256 + 128 + 2*m] + Sws[h*256 + 192 + 2*m]);
      S.y = (Sws[h*256 + 2*m + 1]       + Sws[h*256 + 64 + 2*m + 1])
          + (Sws[h*256 + 128 + 2*m + 1] + Sws[h*256 + 192 + 2*m + 1]);
      float qn = -aterm * frcp(1.0f + bterm) * 0.5f;
      S.x += qn * 2.0f * glxn;
      S.y += qn * 2.0f * glyn;
      // C~ = C - (C dL - u S / 8192)
      c32 y = cmul(Cf, dL);
      c32 uS = cmul(u, S);
      y.x -= uS.x * (1.0f/8192.0f);
      y.y -= uS.y * (1.0f/8192.0f);
      c32 Ct = csub(Cf, y);
      // stage-B vectors
      c32 Bc = make_float2(Bin[(h*NN+m)*2], Bin[(h*NN+m)*2+1]);
      c32 Qc = cconjf(Pf);    // lane<32: Pf unconjugated
      c32 v00 = cmul(Bc, Ct), v01 = cmul(Bc, Qc), v10 = cmul(Pf, Ct), v11 = cmul(Pf, Qc);
      vs[0][m] = make_float2(v00.x*dt, v00.y*dt);
      vs[1][m] = make_float2(v01.x*dt, v01.y*dt);
      vs[2][m] = make_float2(v10.x*dt, v10.y*dt);
      vs[3][m] = make_float2(v11.x*dt, v11.y*dt);
      wdt_s[m] = make_float2(wr*dt, wi*dt);
      // Nyquist X[4096] = sum Re(v00*dt)
      float s00 = v00.x * dt;
      #pragma unroll
      for (int off = 16; off >= 1; off >>= 1) s00 += __shfl_xor(s00, off, 64);
      if (m == 0) Xs[MF] = make_float2(s00, 0.0f);
    }
  }
  __syncthreads();

  // ---- Cauchy at z_j = 2i tan(pi j/L), 4 nodes/thread ----
  {
    float Tq[4], t2[4];
    c32 a00[4], a01[4], a10[4], a11[4];
    #pragma unroll
    for (int q = 0; q < 4; q++) {
      int j = tid + (q << 10);
      float rev = (float)j * (1.0f/16384.0f);
      float sn = __builtin_amdgcn_sinf(rev);
      float cs = __builtin_amdgcn_cosf(rev);
      float T = sn * frcp(cs);
      Tq[q] = T; t2[q] = 2.0f*T;
      a00[q] = make_float2(0,0); a01[q] = make_float2(0,0);
      a10[q] = make_float2(0,0); a11[q] = make_float2(0,0);
    }
    #pragma unroll 2
    for (int n = 0; n < NN; n++) {
      c32 w = wdt_s[n];
      float nr  = -w.x;
      float nr2 = nr*nr;
      float wy  = w.y;
      c32 v0 = vs[0][n], v1 = vs[1][n], v2 = vs[2][n], v3 = vs[3][n];
      #pragma unroll
      for (int q = 0; q < 4; q++) {
        float d1i = t2[q] - wy;
        float d2i = t2[q] + wy;
        float n1 = fmaf(d1i, d1i, nr2);
        float n2 = fmaf(d2i, d2i, nr2);
        float ip = frcp(n1*n2);
        float inv1 = n2*ip, inv2 = n1*ip;
        float c1x = nr*inv1, c1y = -d1i*inv1;
        float c2x = nr*inv2, c2y = -d2i*inv2;
        float sx = c1x + c2x, dxx = c1x - c2x;
        float sy = c1y + c2y, dyy = c1y - c2y;
        a00[q].x = fmaf(v0.x, sx, fmaf(-v0.y, dyy, a00[q].x));
        a00[q].y = fmaf(v0.x, sy, fmaf( v0.y, dxx, a00[q].y));
        a01[q].x = fmaf(v1.x, sx, fmaf(-v1.y, dyy, a01[q].x));
        a01[q].y = fmaf(v1.x, sy, fmaf( v1.y, dxx, a01[q].y));
        a10[q].x = fmaf(v2.x, sx, fmaf(-v2.y, dyy, a10[q].x));
        a10[q].y = fmaf(v2.x, sy, fmaf( v2.y, dxx, a10[q].y));
        a11[q].x = fmaf(v3.x, sx, fmaf(-v3.y, dyy, a11[q].x));
        a11[q].y = fmaf(v3.x, sy, fmaf( v3.y, dxx, a11[q].y));
      }
    }
    #pragma unroll
    for (int q = 0; q < 4; q++) {
      float denx = 1.0f + a11[q].x, deny = a11[q].y;
      float idn = frcp(fmaf(denx, denx, deny*deny));
      c32 invden = make_float2(denx*idn, -deny*idn);
      c32 kf = csub(a00[q], cmul(cmul(a01[q], a10[q]), invden));
      float T = Tq[q];
      Xs[tid + (q << 10)] = make_float2(kf.x - T*kf.y, kf.y + T*kf.x);  // *(1+iT)
    }
  }
  __syncthreads();

  // ---- real-irfft packing: Z[k] = (E[k] + i*O[k]) / MF ----
  const float invM = 1.0f / (float)MF;
  #pragma unroll
  for (int qq = 0; qq < 4; qq++) {
    int k = tid + (qq << 10);
    c32 Xk = Xs[k];
    c32 Xm = Xs[MF - k];
    float Ex = 0.5f*(Xk.x + Xm.x), Ey = 0.5f*(Xk.y - Xm.y);
    float Ox = 0.5f*(Xk.x - Xm.x), Oy = 0.5f*(Xk.y + Xm.y);
    float rev = (float)k * (1.0f/8192.0f);
    float cs = __builtin_amdgcn_cosf(rev);
    float sn = __builtin_amdgcn_sinf(rev);
    float Orx = Ox*cs - Oy*sn;
    float Ory = Ox*sn + Oy*cs;
    Zs[k] = make_float2((Ex - Ory)*invM, (Ey + Orx)*invM);
  }
  __syncthreads();

  // ---- 6-stage radix-4 Stockham inverse FFT (twiddle sign +) ----
  c32* srcf = Zs;
  c32* dstf = Xs;
  int sstride = 1;
  #pragma unroll
  for (int st = 0; st < 6; st++) {
    int jm = tid & ~(sstride - 1);
    float rev = (float)jm * (1.0f/4096.0f);
    float sn = __builtin_amdgcn_sinf(rev);
    float cs = __builtin_amdgcn_cosf(rev);
    c32 w1 = make_float2(cs, sn);
    c32 w2 = cmul(w1, w1);
    c32 w3 = cmul(w2, w1);
    c32 a = srcf[tid];
    c32 b = srcf[tid + 1024];
    c32 c = srcf[tid + 2048];
    c32 d = srcf[tid + 3072];
    c32 apc = cadd(a, c), amc = csub(a, c);
    c32 bpd = cadd(b, d), bmd = csub(b, d);
    int wb = tid + 3*jm;
    dstf[wb] = cadd(apc, bpd);
    dstf[wb + sstride]   = cmul(w1, make_float2(amc.x - bmd.y, amc.y + bmd.x));
    dstf[wb + 2*sstride] = cmul(w2, csub(apc, bpd));
    dstf[wb + 3*sstride] = cmul(w3, make_float2(amc.x + bmd.y, amc.y - bmd.x));
    __syncthreads();
    c32* t = srcf; srcf = dstf; dstf = t;
    sstride <<= 2;
  }

  // even stage count -> result in Zs (= srcf); z[m] = (x[2m], x[2m+1])
  {
    float4* o4 = (float4*)(out + (size_t)h*MF);
    const float4* s4 = (const float4*)srcf;
    o4[tid] = s4[tid];
    o4[tid + 1024] = s4[tid + 1024];
  }
}

extern "C" void kernel_launch(void* const* d_in, const int* in_sizes, int n_in,
                              void* d_out, int out_size, void* d_ws, size_t ws_size,
                              hipStream_t stream) {
  const float* log_dt = (const float*)d_in[0];
  const float* invwr  = (const float*)d_in[1];
  const float* wimag  = (const float*)d_in[2];
  const float* P      = (const float*)d_in[3];
  const float* B      = (const float*)d_in[4];
  const float* C      = (const float*)d_in[5];
  float* Sws = (float*)d_ws;                 // 1024 blocks * 64 floats = 256 KB
  c32*   out = (c32*)d_out;                  // (H,8192) fp32 = (H,4096) c32
  (void)in_sizes; (void)n_in; (void)out_size; (void)ws_size;

  ssk_S<<<4*HH, 512, 0, stream>>>(log_dt, invwr, wimag, P, C, Sws);
  ssk_B<<<HH, 1024, 0, stream>>>(log_dt, invwr, wimag, P, B, C, Sws, out);
}

// Round 12
// 73.897 us; speedup vs baseline: 1.4965x; 1.4965x over previous
//
#include <hip/hip_runtime.h>

// SSKernelNPLR, 2-kernel pipeline. H=256, N=32 (M=64 conj-extended), R=1, L=8192.
// K1 ssk_S (grid 1024, 512 thr, launch_bounds(512,4) => empirical VGPR cap 64):
//    contour with 8-lane node groups. Lane l of a group owns 4 state-pairs
//    (m = (l&7)*4+k), params streamed from LDS. Per node j: 4 G-folds -> regs +
//    local (a,b); 3-level shfl_xor(1,2,4) group reduce -> (a_j,b_j);
//    q_j = z a/(1+b); S_m += q-fold into 8 VGPRs. 16 node-iters/thread.
//    Reduce: masked butterfly (xor 8,16,32) -> LDS -> 64-thread cross-wave sum
//    -> Sws [h][part][2m+bit].
//    NOTE launch-bounds arg2 empirical law on this toolchain: VGPR cap = 256/arg2
//    (r5/r6/r7/r9/r11 evidence); arg2=8 forced cap 32 and spilled.
// K2 ssk_B (grid 256, 1024 thr): per-head algebra redo + combine 4 S partials +
//    z=-1 node -> C~ -> v-vectors; Cauchy at z_j = 2i tan(pi j/L) + Woodbury
//    + (1+iT); real-irfft packing; 6-stage radix-4 Stockham inverse FFT -> out.

#define HH 256
#define NN 32
#define MF 4096

typedef float2 c32;

__device__ __forceinline__ c32 cmul(c32 a, c32 b){ return make_float2(a.x*b.x - a.y*b.y, a.x*b.y + a.y*b.x); }
__device__ __forceinline__ c32 cadd(c32 a, c32 b){ return make_float2(a.x+b.x, a.y+b.y); }
__device__ __forceinline__ c32 csub(c32 a, c32 b){ return make_float2(a.x-b.x, a.y-b.y); }
__device__ __forceinline__ c32 cconjf(c32 a){ return make_float2(a.x, -a.y); }
__device__ __forceinline__ float frcp(float x){ return __builtin_amdgcn_rcpf(x); }

// ---------------- K1: register-fused contour (8-lane node groups) ----------
__global__ __launch_bounds__(512, 4)
void ssk_S(const float* __restrict__ log_dt, const float* __restrict__ invwr,
           const float* __restrict__ wim, const float* __restrict__ Pin,
           const float* __restrict__ Cin, float* __restrict__ Sws)
{
  __shared__ __align__(16) float4 ta_s[32];   // (d.x, d.y, pc.x, pc.y)
  __shared__ c32 pu_s[32];
  __shared__ float red[8*64];                 // [wave][component]
  const int bid = blockIdx.x;
  const int h = bid >> 2;
  const int base = (bid & 3) << 10;           // 0,1024,2048,3072
  const int tid = threadIdx.x;

  // ---- A1: per-head algebra (wave 0; m = tid, conj half for m>=32) ----
  if (tid < 64) {
    const int n = tid & 31;
    const bool cj = tid >= 32;
    const float dt = expf(log_dt[h]);
    float wr = -expf(invwr[h*NN + n]);
    float wi = wim[h*NN + n];
    if (cj) wi = -wi;
    const float tdt = 2.0f / dt;
    float dr = tdt - wr, di = -wi;
    float invd = 1.0f / (dr*dr + di*di);
    c32 D = make_float2(dr*invd, -di*invd);   // 1/(2/dt - w)
    c32 E = make_float2(tdt + wr, wi);        // 2/dt + w
    c32 Pf = make_float2(Pin[(h*NN+n)*2], Pin[(h*NN+n)*2+1]);
    if (cj) Pf.y = -Pf.y;
    c32 Cf = make_float2(Cin[(h*NN+n)*2], Cin[(h*NN+n)*2+1]);
    if (cj) Cf.y = -Cf.y;
    float rm = (Pf.x*Pf.x + Pf.y*Pf.y) * D.x; // Rm = 1 + sum |Pf|^2 Re(D)
    #pragma unroll
    for (int off = 32; off >= 1; off >>= 1) rm += __shfl_xor(rm, off, 64);
    rm += 1.0f;
    c32 Rc = cmul(cconjf(Pf), D);
    float invrm = 1.0f / rm;
    Rc.x *= invrm; Rc.y *= invrm;
    c32 RP = cmul(Rc, Pf);
    #pragma unroll
    for (int off = 32; off >= 1; off >>= 1) {
      RP.x += __shfl_xor(RP.x, off, 64);
      RP.y += __shfl_xor(RP.y, off, 64);
    }
    c32 Q2 = cconjf(Pf);
    c32 s  = csub(cmul(Rc, E), cmul(RP, Q2));
    c32 u  = cadd(Q2, s);                     // dA = diag(dd) - pp u^T
    c32 dd = cmul(D, E);
    c32 pp = cmul(D, Pf);
    c32 pc = cmul(pp, Cf);
    c32 pu = cmul(pp, u);
    if (tid < 32) {
      ta_s[tid] = make_float4(dd.x, dd.y, pc.x, pc.y);
      pu_s[tid] = pu;
    }
  }
  __syncthreads();

  const int sub = tid & 7;                    // 4-state slice
  const int grp = tid >> 3;                   // node slot 0..63

  float ssx[4], ssy[4];
  #pragma unroll
  for (int k = 0; k < 4; k++) { ssx[k] = 0.0f; ssy[k] = 0.0f; }

  for (int it = 0; it < 16; it++) {
    const int j = base + (it << 6) + grp;     // node index 0..4095
    float rev = (float)j * (1.0f/8192.0f);
    float zx = __builtin_amdgcn_cosf(rev);
    float zy = __builtin_amdgcn_sinf(rev);

    float fsx[4], fsy[4], fdx[4], fdy[4];
    float ax = 0.0f, ay = 0.0f, bx = 0.0f, by = 0.0f;
    #pragma unroll
    for (int k = 0; k < 4; k++) {
      float4 ta = ta_s[sub*4 + k];            // LDS-streamed params
      c32 pu = pu_s[sub*4 + k];
      float dxx = zx - ta.x;
      float dy1 = zy - ta.y;
      float dy2 = zy + ta.y;
      float xx  = dxx*dxx;
      float n1  = fmaf(dy1, dy1, xx);
      float n2  = fmaf(dy2, dy2, xx);
      float ip  = frcp(n1*n2);
      float i1  = n2*ip, i2 = n1*ip;
      float glx = dxx*i1, gly = -dy1*i1;      // 1/(z - d)
      float ghx = dxx*i2, ghy = -dy2*i2;      // 1/(z - conj d)
      float sx = glx + ghx, sy = gly + ghy;
      float dxg = glx - ghx, dyg = gly - ghy;
      fsx[k] = sx; fsy[k] = sy; fdx[k] = dxg; fdy[k] = dyg;
      ax = fmaf(ta.z, sx, fmaf(-ta.w, dyg, ax));
      ay = fmaf(ta.z, sy, fmaf( ta.w, dxg, ay));
      bx = fmaf(pu.x, sx, fmaf(-pu.y, dyg, bx));
      by = fmaf(pu.x, sy, fmaf( pu.y, dxg, by));
    }
    // 8-lane group reduce: lanes hold disjoint state slices
    ax += __shfl_xor(ax, 1, 64); ax += __shfl_xor(ax, 2, 64); ax += __shfl_xor(ax, 4, 64);
    ay += __shfl_xor(ay, 1, 64); ay += __shfl_xor(ay, 2, 64); ay += __shfl_xor(ay, 4, 64);
    bx += __shfl_xor(bx, 1, 64); bx += __shfl_xor(bx, 2, 64); bx += __shfl_xor(bx, 4, 64);
    by += __shfl_xor(by, 1, 64); by += __shfl_xor(by, 2, 64); by += __shfl_xor(by, 4, 64);
    // q = z a/(1+b)  (group-redundant)
    float denx = 1.0f + bx, deny = by;
    float idn = frcp(fmaf(denx, denx, deny*deny));
    float tx = (ax*denx + ay*deny)*idn;
    float ty = (ay*denx - ax*deny)*idn;
    float qx = zx*tx - zy*ty;
    float qy = zx*ty + zy*tx;
    if (j == 0) { qx *= 0.5f; qy *= 0.5f; }   // self-conj node z=1
    #pragma unroll
    for (int k = 0; k < 4; k++) {
      ssx[k] = fmaf(qx, fsx[k], fmaf(-qy, fsy[k], ssx[k]));
      ssy[k] = fmaf(qx, fdy[k], fmaf( qy, fdx[k], ssy[k]));
    }
  }

  // ---- masked wave butterfly: combine lanes with the same sub ----
  #pragma unroll
  for (int off = 8; off <= 32; off <<= 1) {
    #pragma unroll
    for (int k = 0; k < 4; k++) {
      ssx[k] += __shfl_xor(ssx[k], off, 64);
      ssy[k] += __shfl_xor(ssy[k], off, 64);
    }
  }
  const int lane = tid & 63;
  const int wv = tid >> 6;
  if (lane < 8) {   // sub == lane for these lanes
    #pragma unroll
    for (int k = 0; k < 4; k++) {
      red[wv*64 + lane*8 + 2*k]     = ssx[k];   // component c = 2m+bit, m=lane*4+k
      red[wv*64 + lane*8 + 2*k + 1] = ssy[k];
    }
  }
  __syncthreads();

  if (tid < 64) {
    float t = 0.0f;
    #pragma unroll
    for (int w = 0; w < 8; w++) t += red[w*64 + tid];
    Sws[bid*64 + tid] = t;    // layout: [h][part][2m+bit]
  }
}

// ---------------- K2: combine + Cauchy/Woodbury + irfft (r9, verified) -----
__global__ __launch_bounds__(1024, 4)
void ssk_B(const float* __restrict__ log_dt, const float* __restrict__ invwr,
           const float* __restrict__ wim, const float* __restrict__ Pin,
           const float* __restrict__ Bin, const float* __restrict__ Cin,
           const float* __restrict__ Sws, c32* __restrict__ out)
{
  __shared__ __align__(16) c32 Xs[4098];   // spectrum / FFT ping
  __shared__ __align__(16) c32 Zs[4096];   // packed seq / FFT pong
  __shared__ c32 wdt_s[NN];
  __shared__ c32 vs[4][NN];
  const int h = blockIdx.x;
  const int tid = threadIdx.x;

  // ---- per-head algebra redo + combine (wave 0) ----
  if (tid < 64) {
    const int n = tid & 31;
    const bool cj = tid >= 32;
    const float dt = expf(log_dt[h]);
    float wr = -expf(invwr[h*NN + n]);
    float wi = wim[h*NN + n];
    if (cj) wi = -wi;
    const float tdt = 2.0f / dt;
    float dr = tdt - wr, di = -wi;
    float invd = 1.0f / (dr*dr + di*di);
    c32 D = make_float2(dr*invd, -di*invd);
    c32 E = make_float2(tdt + wr, wi);
    c32 Pf = make_float2(Pin[(h*NN+n)*2], Pin[(h*NN+n)*2+1]);
    if (cj) Pf.y = -Pf.y;
    c32 Cf = make_float2(Cin[(h*NN+n)*2], Cin[(h*NN+n)*2+1]);
    if (cj) Cf.y = -Cf.y;
    float rm = (Pf.x*Pf.x + Pf.y*Pf.y) * D.x;
    #pragma unroll
    for (int off = 32; off >= 1; off >>= 1) rm += __shfl_xor(rm, off, 64);
    rm += 1.0f;
    c32 Rc = cmul(cconjf(Pf), D);
    float invrm = 1.0f / rm;
    Rc.x *= invrm; Rc.y *= invrm;
    c32 RP = cmul(Rc, Pf);
    #pragma unroll
    for (int off = 32; off >= 1; off >>= 1) {
      RP.x += __shfl_xor(RP.x, off, 64);
      RP.y += __shfl_xor(RP.y, off, 64);
    }
    c32 Q2 = cconjf(Pf);
    c32 s  = csub(cmul(Rc, E), cmul(RP, Q2));
    c32 u  = cadd(Q2, s);
    c32 dd = cmul(D, E);
    c32 pp = cmul(D, Pf);
    c32 pc = cmul(pp, Cf);
    c32 pu = cmul(pp, u);

    // z = -1 node: g = conj(-1-d)/|.|^2 ; a,b real (conj-pair fold)
    float dxxn = -1.0f - dd.x;
    float nn1 = fmaf(dxxn, dxxn, dd.y*dd.y);
    float ii = frcp(nn1);
    float glxn = dxxn*ii, glyn = dd.y*ii;
    float aterm = 2.0f*(pc.x*glxn - pc.y*glyn);
    float bterm = 2.0f*(pu.x*glxn - pu.y*glyn);
    #pragma unroll
    for (int off = 16; off >= 1; off >>= 1) {
      aterm += __shfl_xor(aterm, off, 64);
      bterm += __shfl_xor(bterm, off, 64);
    }

    if (tid < 32) {
      const int m = tid;
      // exact diagonal part d^8192
      c32 dL = dd;
      #pragma unroll
      for (int i2 = 0; i2 < 13; i2++) dL = cmul(dL, dL);
      // total S: 4 partials + z=-1 node (q real, half weight)
      c32 S;
      S.x = (Sws[h*256 + 2*m]       + Sws[h*256 + 64 + 2*m])
          + (Sws[h*256 + 128 + 2*m] + Sws[h*256 + 192 + 2*m]);
      S.y = (Sws[h*256 + 2*m + 1]       + Sws[h*256 + 64 + 2*m + 1])
          + (Sws[h*256 + 128 + 2*m + 1] + Sws[h*256 + 192 + 2*m + 1]);
      float qn = -aterm * frcp(1.0f + bterm) * 0.5f;
      S.x += qn * 2.0f * glxn;
      S.y += qn * 2.0f * glyn;
      // C~ = C - (C dL - u S / 8192)
      c32 y = cmul(Cf, dL);
      c32 uS = cmul(u, S);
      y.x -= uS.x * (1.0f/8192.0f);
      y.y -= uS.y * (1.0f/8192.0f);
      c32 Ct = csub(Cf, y);
      // stage-B vectors
      c32 Bc = make_float2(Bin[(h*NN+m)*2], Bin[(h*NN+m)*2+1]);
      c32 Qc = cconjf(Pf);    // lane<32: Pf unconjugated
      c32 v00 = cmul(Bc, Ct), v01 = cmul(Bc, Qc), v10 = cmul(Pf, Ct), v11 = cmul(Pf, Qc);
      vs[0][m] = make_float2(v00.x*dt, v00.y*dt);
      vs[1][m] = make_float2(v01.x*dt, v01.y*dt);
      vs[2][m] = make_float2(v10.x*dt, v10.y*dt);
      vs[3][m] = make_float2(v11.x*dt, v11.y*dt);
      wdt_s[m] = make_float2(wr*dt, wi*dt);
      // Nyquist X[4096] = sum Re(v00*dt)
      float s00 = v00.x * dt;
      #pragma unroll
      for (int off = 16; off >= 1; off >>= 1) s00 += __shfl_xor(s00, off, 64);
      if (m == 0) Xs[MF] = make_float2(s00, 0.0f);
    }
  }
  __syncthreads();

  // ---- Cauchy at z_j = 2i tan(pi j/L), 4 nodes/thread ----
  {
    float Tq[4], t2[4];
    c32 a00[4], a01[4], a10[4], a11[4];
    #pragma unroll
    for (int q = 0; q < 4; q++) {
      int j = tid + (q << 10);
      float rev = (float)j * (1.0f/16384.0f);
      float sn = __builtin_amdgcn_sinf(rev);
      float cs = __builtin_amdgcn_cosf(rev);
      float T = sn * frcp(cs);
      Tq[q] = T; t2[q] = 2.0f*T;
      a00[q] = make_float2(0,0); a01[q] = make_float2(0,0);
      a10[q] = make_float2(0,0); a11[q] = make_float2(0,0);
    }
    #pragma unroll 2
    for (int n = 0; n < NN; n++) {
      c32 w = wdt_s[n];
      float nr  = -w.x;
      float nr2 = nr*nr;
      float wy  = w.y;
      c32 v0 = vs[0][n], v1 = vs[1][n], v2 = vs[2][n], v3 = vs[3][n];
      #pragma unroll
      for (int q = 0; q < 4; q++) {
        float d1i = t2[q] - wy;
        float d2i = t2[q] + wy;
        float n1 = fmaf(d1i, d1i, nr2);
        float n2 = fmaf(d2i, d2i, nr2);
        float ip = frcp(n1*n2);
        float inv1 = n2*ip, inv2 = n1*ip;
        float c1x = nr*inv1, c1y = -d1i*inv1;
        float c2x = nr*inv2, c2y = -d2i*inv2;
        float sx = c1x + c2x, dxx = c1x - c2x;
        float sy = c1y + c2y, dyy = c1y - c2y;
        a00[q].x = fmaf(v0.x, sx, fmaf(-v0.y, dyy, a00[q].x));
        a00[q].y = fmaf(v0.x, sy, fmaf( v0.y, dxx, a00[q].y));
        a01[q].x = fmaf(v1.x, sx, fmaf(-v1.y, dyy, a01[q].x));
        a01[q].y = fmaf(v1.x, sy, fmaf( v1.y, dxx, a01[q].y));
        a10[q].x = fmaf(v2.x, sx, fmaf(-v2.y, dyy, a10[q].x));
        a10[q].y = fmaf(v2.x, sy, fmaf( v2.y, dxx, a10[q].y));
        a11[q].x = fmaf(v3.x, sx, fmaf(-v3.y, dyy, a11[q].x));
        a11[q].y = fmaf(v3.x, sy, fmaf( v3.y, dxx, a11[q].y));
      }
    }
    #pragma unroll
    for (int q = 0; q < 4; q++) {
      float denx = 1.0f + a11[q].x, deny = a11[q].y;
      float idn = frcp(fmaf(denx, denx, deny*deny));
      c32 invden = make_float2(denx*idn, -deny*idn);
      c32 kf = csub(a00[q], cmul(cmul(a01[q], a10[q]), invden));
      float T = Tq[q];
      Xs[tid + (q << 10)] = make_float2(kf.x - T*kf.y, kf.y + T*kf.x);  // *(1+iT)
    }
  }
  __syncthreads();

  // ---- real-irfft packing: Z[k] = (E[k] + i*O[k]) / MF ----
  const float invM = 1.0f / (float)MF;
  #pragma unroll
  for (int qq = 0; qq < 4; qq++) {
    int k = tid + (qq << 10);
    c32 Xk = Xs[k];
    c32 Xm = Xs[MF - k];
    float Ex = 0.5f*(Xk.x + Xm.x), Ey = 0.5f*(Xk.y - Xm.y);
    float Ox = 0.5f*(Xk.x - Xm.x), Oy = 0.5f*(Xk.y + Xm.y);
    float rev = (float)k * (1.0f/8192.0f);
    float cs = __builtin_amdgcn_cosf(rev);
    float sn = __builtin_amdgcn_sinf(rev);
    float Orx = Ox*cs - Oy*sn;
    float Ory = Ox*sn + Oy*cs;
    Zs[k] = make_float2((Ex - Ory)*invM, (Ey + Orx)*invM);
  }
  __syncthreads();

  // ---- 6-stage radix-4 Stockham inverse FFT (twiddle sign +) ----
  c32* srcf = Zs;
  c32* dstf = Xs;
  int sstride = 1;
  #pragma unroll
  for (int st = 0; st < 6; st++) {
    int jm = tid & ~(sstride - 1);
    float rev = (float)jm * (1.0f/4096.0f);
    float sn = __builtin_amdgcn_sinf(rev);
    float cs = __builtin_amdgcn_cosf(rev);
    c32 w1 = make_float2(cs, sn);
    c32 w2 = cmul(w1, w1);
    c32 w3 = cmul(w2, w1);
    c32 a = srcf[tid];
    c32 b = srcf[tid + 1024];
    c32 c = srcf[tid + 2048];
    c32 d = srcf[tid + 3072];
    c32 apc = cadd(a, c), amc = csub(a, c);
    c32 bpd = cadd(b, d), bmd = csub(b, d);
    int wb = tid + 3*jm;
    dstf[wb] = cadd(apc, bpd);
    dstf[wb + sstride]   = cmul(w1, make_float2(amc.x - bmd.y, amc.y + bmd.x));
    dstf[wb + 2*sstride] = cmul(w2, csub(apc, bpd));
    dstf[wb + 3*sstride] = cmul(w3, make_float2(amc.x + bmd.y, amc.y - bmd.x));
    __syncthreads();
    c32* t = srcf; srcf = dstf; dstf = t;
    sstride <<= 2;
  }

  // even stage count -> result in Zs (= srcf); z[m] = (x[2m], x[2m+1])
  {
    float4* o4 = (float4*)(out + (size_t)h*MF);
    const float4* s4 = (const float4*)srcf;
    o4[tid] = s4[tid];
    o4[tid + 1024] = s4[tid + 1024];
  }
}

extern "C" void kernel_launch(void* const* d_in, const int* in_sizes, int n_in,
                              void* d_out, int out_size, void* d_ws, size_t ws_size,
                              hipStream_t stream) {
  const float* log_dt = (const float*)d_in[0];
  const float* invwr  = (const float*)d_in[1];
  const float* wimag  = (const float*)d_in[2];
  const float* P      = (const float*)d_in[3];
  const float* B      = (const float*)d_in[4];
  const float* C      = (const float*)d_in[5];
  float* Sws = (float*)d_ws;                 // 1024 blocks * 64 floats = 256 KB
  c32*   out = (c32*)d_out;                  // (H,8192) fp32 = (H,4096) c32
  (void)in_sizes; (void)n_in; (void)out_size; (void)ws_size;

  ssk_S<<<4*HH, 512, 0, stream>>>(log_dt, invwr, wimag, P, C, Sws);
  ssk_B<<<HH, 1024, 0, stream>>>(log_dt, invwr, wimag, P, B, C, Sws, out);
}

// Round 13
// 72.587 us; speedup vs baseline: 1.5235x; 1.0181x over previous
//
#include <hip/hip_runtime.h>

// SSKernelNPLR, 2-kernel pipeline. H=256, N=32 (M=64 conj-extended), R=1, L=8192.
// K1 ssk_S (grid 1024, 512 thr, launch_bounds(512,4) -> VGPR cap 64):
//    contour with 4-lane (quad) node groups, 8 state-pairs/lane.
//    Loop1 per node: product-form iw = 1/[(z-d)(z-conj d)] stored (2 reg/state);
//    a,b accumulated via pair-fold numerators (alpha*z - beta)*iw.
//    Quad shfl_xor(1,2) reduce -> (a_j,b_j); q_j = z a/(1+b).
//    Loop2: S.x += Re[(q iw)(2z - 2Re d)], S.y += 2Im(d) Re(q iw).
//    8 node-iters/thread (1024 nodes/block, 4 blocks/h). Reduce: masked
//    butterfly (xor 4..32) -> LDS -> 64-thread cross-wave sum ->
//    Sws [h][part][2m+bit]  (identical layout to r12).
// K2 ssk_B (grid 256, 1024 thr): combine + C~ + poly-form Cauchy at
//    z = 2i tan(pi j/L): per conj-pair, contribution = (-beta + i alpha t2)*iw,
//    iw = 1/(aw - t2^2 + i tnw t2); Woodbury + (1+iT); real-irfft packing;
//    6-stage radix-4 Stockham inverse FFT -> out.

#define HH 256
#define NN 32
#define MF 4096

typedef float2 c32;

__device__ __forceinline__ c32 cmul(c32 a, c32 b){ return make_float2(a.x*b.x - a.y*b.y, a.x*b.y + a.y*b.x); }
__device__ __forceinline__ c32 cadd(c32 a, c32 b){ return make_float2(a.x+b.x, a.y+b.y); }
__device__ __forceinline__ c32 csub(c32 a, c32 b){ return make_float2(a.x-b.x, a.y-b.y); }
__device__ __forceinline__ c32 cconjf(c32 a){ return make_float2(a.x, -a.y); }
__device__ __forceinline__ float frcp(float x){ return __builtin_amdgcn_rcpf(x); }

// ---------------- K1: contour, quad node groups, iw-compressed ------------
__global__ __launch_bounds__(512, 4)
void ssk_S(const float* __restrict__ log_dt, const float* __restrict__ invwr,
           const float* __restrict__ wim, const float* __restrict__ Pin,
           const float* __restrict__ Cin, float* __restrict__ Sws)
{
  // padded index pm = m + (m>>3) -> quad lanes hit distinct bank groups
  __shared__ __align__(16) float4 tA[36];   // (d.x, d.y, alpha_a, beta_a)
  __shared__ c32 tB[36];                    // (alpha_b, beta_b)
  __shared__ c32 tC[36];                    // (2Re d, 2Im d)
  __shared__ float red[8*64];               // [wave][component]
  const int bid = blockIdx.x;
  const int h = bid >> 2;
  const int base = (bid & 3) << 10;         // 0,1024,2048,3072
  const int tid = threadIdx.x;

  // ---- A1: per-head algebra (wave 0; m = tid, conj half for m>=32) ----
  if (tid < 64) {
    const int n = tid & 31;
    const bool cj = tid >= 32;
    const float dt = expf(log_dt[h]);
    float wr = -expf(invwr[h*NN + n]);
    float wi = wim[h*NN + n];
    if (cj) wi = -wi;
    const float tdt = 2.0f / dt;
    float dr = tdt - wr, di = -wi;
    float invd = 1.0f / (dr*dr + di*di);
    c32 D = make_float2(dr*invd, -di*invd);   // 1/(2/dt - w)
    c32 E = make_float2(tdt + wr, wi);        // 2/dt + w
    c32 Pf = make_float2(Pin[(h*NN+n)*2], Pin[(h*NN+n)*2+1]);
    if (cj) Pf.y = -Pf.y;
    c32 Cf = make_float2(Cin[(h*NN+n)*2], Cin[(h*NN+n)*2+1]);
    if (cj) Cf.y = -Cf.y;
    float rm = (Pf.x*Pf.x + Pf.y*Pf.y) * D.x; // Rm = 1 + sum |Pf|^2 Re(D)
    #pragma unroll
    for (int off = 32; off >= 1; off >>= 1) rm += __shfl_xor(rm, off, 64);
    rm += 1.0f;
    c32 Rc = cmul(cconjf(Pf), D);
    float invrm = 1.0f / rm;
    Rc.x *= invrm; Rc.y *= invrm;
    c32 RP = cmul(Rc, Pf);
    #pragma unroll
    for (int off = 32; off >= 1; off >>= 1) {
      RP.x += __shfl_xor(RP.x, off, 64);
      RP.y += __shfl_xor(RP.y, off, 64);
    }
    c32 Q2 = cconjf(Pf);
    c32 s  = csub(cmul(Rc, E), cmul(RP, Q2));
    c32 u  = cadd(Q2, s);                     // dA = diag(dd) - pp u^T
    c32 dd = cmul(D, E);
    c32 pp = cmul(D, Pf);
    c32 pc = cmul(pp, Cf);
    c32 pu = cmul(pp, u);
    if (tid < 32) {
      const int pm = tid + (tid >> 3);
      float ba = 2.0f*(pc.x*dd.x + pc.y*dd.y);
      float bb = 2.0f*(pu.x*dd.x + pu.y*dd.y);
      tA[pm] = make_float4(dd.x, dd.y, pc.x + pc.x, ba);
      tB[pm] = make_float2(pu.x + pu.x, bb);
      tC[pm] = make_float2(dd.x + dd.x, dd.y + dd.y);
    }
  }
  __syncthreads();

  const int sub = tid & 3;                    // 8-state slice
  const int grp = tid >> 2;                   // node slot 0..127
  const int pbase = sub * 9;                  // padded param base

  float ssx[8], ssy[8];
  #pragma unroll
  for (int k = 0; k < 8; k++) { ssx[k] = 0.0f; ssy[k] = 0.0f; }

  for (int it = 0; it < 8; it++) {
    const int j = base + (it << 7) + grp;     // node index 0..4095
    float rev = (float)j * (1.0f/8192.0f);
    float zx = __builtin_amdgcn_cosf(rev);
    float zy = __builtin_amdgcn_sinf(rev);
    float t2zx = zx + zx;
    float t2zy = zy + zy;

    float iwxA[8], iwyA[8];
    float ax = 0.0f, ay = 0.0f, bx = 0.0f, by = 0.0f;
    #pragma unroll
    for (int k = 0; k < 8; k++) {
      float4 A = tA[pbase + k];               // d.x, d.y, aa, ba
      c32 Bv = tB[pbase + k];                 // ab, bb
      float dxx = zx - A.x;
      float dy1 = zy - A.y;
      float dy2 = zy + A.y;
      float xx  = dxx*dxx;
      float n1  = fmaf(dy1, dy1, xx);
      float n2  = fmaf(dy2, dy2, xx);
      float ip  = frcp(n1*n2);
      float p12 = dy1*dy2;
      float wvx = xx - p12;                   // Re[(z-d)(z-conj d)]
      float wvyn = dxx*t2zy;                  // Im[...] = dxx*(dy1+dy2)
      float iwx = wvx*ip;
      float iwy = -wvyn*ip;
      iwxA[k] = iwx; iwyA[k] = iwy;
      // a += (aa*z - ba)*iw ; b += (ab*z - bb)*iw
      float nax = fmaf(A.z, zx, -A.w);
      float nay = A.z*zy;
      ax = fmaf(nax, iwx, fmaf(-nay, iwy, ax));
      ay = fmaf(nax, iwy, fmaf( nay, iwx, ay));
      float nbx = fmaf(Bv.x, zx, -Bv.y);
      float nby = Bv.x*zy;
      bx = fmaf(nbx, iwx, fmaf(-nby, iwy, bx));
      by = fmaf(nbx, iwy, fmaf( nby, iwx, by));
    }
    // quad reduce: lanes of the 4-group hold disjoint state slices
    ax += __shfl_xor(ax, 1, 64); ax += __shfl_xor(ax, 2, 64);
    ay += __shfl_xor(ay, 1, 64); ay += __shfl_xor(ay, 2, 64);
    bx += __shfl_xor(bx, 1, 64); bx += __shfl_xor(bx, 2, 64);
    by += __shfl_xor(by, 1, 64); by += __shfl_xor(by, 2, 64);
    // q = z a/(1+b)  (quad-redundant)
    float denx = 1.0f + bx, deny = by;
    float idn = frcp(fmaf(denx, denx, deny*deny));
    float tx = (ax*denx + ay*deny)*idn;
    float ty = (ay*denx - ax*deny)*idn;
    float qx = zx*tx - zy*ty;
    float qy = zx*ty + zy*tx;
    if (j == 0) { qx *= 0.5f; qy *= 0.5f; }   // self-conj node z=1
    #pragma unroll
    for (int k = 0; k < 8; k++) {
      c32 Cv = tC[pbase + k];                 // (2Re d, 2Im d)
      float iwx = iwxA[k], iwy = iwyA[k];
      float t1x = fmaf(qx, iwx, -qy*iwy);     // Re(q*iw)
      float t1y = fmaf(qx, iwy,  qy*iwx);     // Im(q*iw)
      float ux  = t2zx - Cv.x;                // 2zx - 2Re d
      ssx[k] = fmaf(t1x, ux, fmaf(-t1y, t2zy, ssx[k]));
      ssy[k] = fmaf(Cv.y, t1x, ssy[k]);
    }
  }

  // ---- masked wave butterfly: combine lanes with the same sub ----
  #pragma unroll
  for (int off = 4; off <= 32; off <<= 1) {
    #pragma unroll
    for (int k = 0; k < 8; k++) {
      ssx[k] += __shfl_xor(ssx[k], off, 64);
      ssy[k] += __shfl_xor(ssy[k], off, 64);
    }
  }
  const int lane = tid & 63;
  const int wv = tid >> 6;
  if (lane < 4) {   // sub == lane here
    #pragma unroll
    for (int k = 0; k < 8; k++) {
      red[wv*64 + lane*16 + 2*k]     = ssx[k];  // component c = 2m+bit, m=lane*8+k
      red[wv*64 + lane*16 + 2*k + 1] = ssy[k];
    }
  }
  __syncthreads();

  if (tid < 64) {
    float t = 0.0f;
    #pragma unroll
    for (int w = 0; w < 8; w++) t += red[w*64 + tid];
    Sws[bid*64 + tid] = t;    // layout: [h][part][2m+bit]
  }
}

// ---------------- K2: combine + poly-Cauchy/Woodbury + irfft --------------
__global__ __launch_bounds__(1024, 4)
void ssk_B(const float* __restrict__ log_dt, const float* __restrict__ invwr,
           const float* __restrict__ wim, const float* __restrict__ Pin,
           const float* __restrict__ Bin, const float* __restrict__ Cin,
           const float* __restrict__ Sws, c32* __restrict__ out)
{
  __shared__ __align__(16) c32 Xs[4098];   // spectrum / FFT ping
  __shared__ __align__(16) c32 Zs[4096];   // packed seq / FFT pong
  __shared__ __align__(16) float4 cs1_s[NN];  // (aw, tnw, a00, b00)
  __shared__ __align__(16) float4 cs2_s[NN];  // (a01, b01, a10, b10)
  __shared__ c32 cs3_s[NN];                   // (a11, b11)
  const int h = blockIdx.x;
  const int tid = threadIdx.x;

  // ---- per-head algebra redo + combine (wave 0) ----
  if (tid < 64) {
    const int n = tid & 31;
    const bool cj = tid >= 32;
    const float dt = expf(log_dt[h]);
    float wr = -expf(invwr[h*NN + n]);
    float wi = wim[h*NN + n];
    if (cj) wi = -wi;
    const float tdt = 2.0f / dt;
    float dr = tdt - wr, di = -wi;
    float invd = 1.0f / (dr*dr + di*di);
    c32 D = make_float2(dr*invd, -di*invd);
    c32 E = make_float2(tdt + wr, wi);
    c32 Pf = make_float2(Pin[(h*NN+n)*2], Pin[(h*NN+n)*2+1]);
    if (cj) Pf.y = -Pf.y;
    c32 Cf = make_float2(Cin[(h*NN+n)*2], Cin[(h*NN+n)*2+1]);
    if (cj) Cf.y = -Cf.y;
    float rm = (Pf.x*Pf.x + Pf.y*Pf.y) * D.x;
    #pragma unroll
    for (int off = 32; off >= 1; off >>= 1) rm += __shfl_xor(rm, off, 64);
    rm += 1.0f;
    c32 Rc = cmul(cconjf(Pf), D);
    float invrm = 1.0f / rm;
    Rc.x *= invrm; Rc.y *= invrm;
    c32 RP = cmul(Rc, Pf);
    #pragma unroll
    for (int off = 32; off >= 1; off >>= 1) {
      RP.x += __shfl_xor(RP.x, off, 64);
      RP.y += __shfl_xor(RP.y, off, 64);
    }
    c32 Q2 = cconjf(Pf);
    c32 s  = csub(cmul(Rc, E), cmul(RP, Q2));
    c32 u  = cadd(Q2, s);
    c32 dd = cmul(D, E);
    c32 pp = cmul(D, Pf);
    c32 pc = cmul(pp, Cf);
    c32 pu = cmul(pp, u);

    // z = -1 node: g = conj(-1-d)/|.|^2 ; a,b real (conj-pair fold)
    float dxxn = -1.0f - dd.x;
    float nn1 = fmaf(dxxn, dxxn, dd.y*dd.y);
    float ii = frcp(nn1);
    float glxn = dxxn*ii, glyn = dd.y*ii;
    float aterm = 2.0f*(pc.x*glxn - pc.y*glyn);
    float bterm = 2.0f*(pu.x*glxn - pu.y*glyn);
    #pragma unroll
    for (int off = 16; off >= 1; off >>= 1) {
      aterm += __shfl_xor(aterm, off, 64);
      bterm += __shfl_xor(bterm, off, 64);
    }

    if (tid < 32) {
      const int m = tid;
      // exact diagonal part d^8192
      c32 dL = dd;
      #pragma unroll
      for (int i2 = 0; i2 < 13; i2++) dL = cmul(dL, dL);
      // total S: 4 partials + z=-1 node (q real, half weight)
      c32 S;
      S.x = (Sws[h*256 + 2*m]       + Sws[h*256 + 64 + 2*m])
          + (Sws[h*256 + 128 + 2*m] + Sws[h*256 + 192 + 2*m]);
      S.y = (Sws[h*256 + 2*m + 1]       + Sws[h*256 + 64 + 2*m + 1])
          + (Sws[h*256 + 128 + 2*m + 1] + Sws[h*256 + 192 + 2*m + 1]);
      float qn = -aterm * frcp(1.0f + bterm) * 0.5f;
      S.x += qn * 2.0f * glxn;
      S.y += qn * 2.0f * glyn;
      // C~ = C - (C dL - u S / 8192)
      c32 y = cmul(Cf, dL);
      c32 uS = cmul(u, S);
      y.x -= uS.x * (1.0f/8192.0f);
      y.y -= uS.y * (1.0f/8192.0f);
      c32 Ct = csub(Cf, y);
      // stage-B tables (poly-Cauchy constants), all dt-scaled
      c32 Bc = make_float2(Bin[(h*NN+m)*2], Bin[(h*NN+m)*2+1]);
      c32 Qc = cconjf(Pf);    // lane<32: Pf unconjugated
      c32 v00 = cmul(Bc, Ct), v01 = cmul(Bc, Qc), v10 = cmul(Pf, Ct), v11 = cmul(Pf, Qc);
      float wx = wr*dt, wy = wi*dt;
      float aw = fmaf(wx, wx, wy*wy);
      float tnw = -(wx + wx);
      float td = dt + dt;
      float a00 = td*v00.x, b00 = td*(v00.x*wx + v00.y*wy);
      float a01 = td*v01.x, b01 = td*(v01.x*wx + v01.y*wy);
      float a10 = td*v10.x, b10 = td*(v10.x*wx + v10.y*wy);
      float a11 = td*v11.x, b11 = td*(v11.x*wx + v11.y*wy);
      cs1_s[m] = make_float4(aw, tnw, a00, b00);
      cs2_s[m] = make_float4(a01, b01, a10, b10);
      cs3_s[m] = make_float2(a11, b11);
      // Nyquist X[4096] = sum Re(v00*dt)
      float s00 = v00.x * dt;
      #pragma unroll
      for (int off = 16; off >= 1; off >>= 1) s00 += __shfl_xor(s00, off, 64);
      if (m == 0) Xs[MF] = make_float2(s00, 0.0f);
    }
  }
  __syncthreads();

  // ---- poly Cauchy at z_j = 2i tan(pi j/L), 4 nodes/thread ----
  {
    float Tq[4], t2[4], t2sq[4];
    c32 a00[4], a01[4], a10[4], a11[4];
    #pragma unroll
    for (int q = 0; q < 4; q++) {
      int j = tid + (q << 10);
      float rev = (float)j * (1.0f/16384.0f);
      float sn = __builtin_amdgcn_sinf(rev);
      float cs = __builtin_amdgcn_cosf(rev);
      float T = sn * frcp(cs);
      Tq[q] = T; t2[q] = 2.0f*T; t2sq[q] = t2[q]*t2[q];
      a00[q] = make_float2(0,0); a01[q] = make_float2(0,0);
      a10[q] = make_float2(0,0); a11[q] = make_float2(0,0);
    }
    #pragma unroll 2
    for (int n = 0; n < NN; n++) {
      float4 C1 = cs1_s[n];   // aw, tnw, a00, b00
      float4 C2 = cs2_s[n];   // a01, b01, a10, b10
      c32   C3 = cs3_s[n];    // a11, b11
      #pragma unroll
      for (int q = 0; q < 4; q++) {
        float wvx = C1.x - t2sq[q];
        float wvy = C1.y * t2[q];
        float r = frcp(fmaf(wvx, wvx, wvy*wvy));
        float iwx = wvx*r;
        float iwy = -wvy*r;
        // acc += (-beta + i alpha t2) * iw, per vector
        float at;
        at = C1.z*t2[q];
        a00[q].x = fmaf(-C1.w, iwx, fmaf(-at, iwy, a00[q].x));
        a00[q].y = fmaf(-C1.w, iwy, fmaf( at, iwx, a00[q].y));
        at = C2.x*t2[q];
        a01[q].x = fmaf(-C2.y, iwx, fmaf(-at, iwy, a01[q].x));
        a01[q].y = fmaf(-C2.y, iwy, fmaf( at, iwx, a01[q].y));
        at = C2.z*t2[q];
        a10[q].x = fmaf(-C2.w, iwx, fmaf(-at, iwy, a10[q].x));
        a10[q].y = fmaf(-C2.w, iwy, fmaf( at, iwx, a10[q].y));
        at = C3.x*t2[q];
        a11[q].x = fmaf(-C3.y, iwx, fmaf(-at, iwy, a11[q].x));
        a11[q].y = fmaf(-C3.y, iwy, fmaf( at, iwx, a11[q].y));
      }
    }
    #pragma unroll
    for (int q = 0; q < 4; q++) {
      float denx = 1.0f + a11[q].x, deny = a11[q].y;
      float idn = frcp(fmaf(denx, denx, deny*deny));
      c32 invden = make_float2(denx*idn, -deny*idn);
      c32 kf = csub(a00[q], cmul(cmul(a01[q], a10[q]), invden));
      float T = Tq[q];
      Xs[tid + (q << 10)] = make_float2(kf.x - T*kf.y, kf.y + T*kf.x);  // *(1+iT)
    }
  }
  __syncthreads();

  // ---- real-irfft packing: Z[k] = (E[k] + i*O[k]) / MF ----
  const float invM = 1.0f / (float)MF;
  #pragma unroll
  for (int qq = 0; qq < 4; qq++) {
    int k = tid + (qq << 10);
    c32 Xk = Xs[k];
    c32 Xm = Xs[MF - k];
    float Ex = 0.5f*(Xk.x + Xm.x), Ey = 0.5f*(Xk.y - Xm.y);
    float Ox = 0.5f*(Xk.x - Xm.x), Oy = 0.5f*(Xk.y + Xm.y);
    float rev = (float)k * (1.0f/8192.0f);
    float cs = __builtin_amdgcn_cosf(rev);
    float sn = __builtin_amdgcn_sinf(rev);
    float Orx = Ox*cs - Oy*sn;
    float Ory = Ox*sn + Oy*cs;
    Zs[k] = make_float2((Ex - Ory)*invM, (Ey + Orx)*invM);
  }
  __syncthreads();

  // ---- 6-stage radix-4 Stockham inverse FFT (twiddle sign +) ----
  c32* srcf = Zs;
  c32* dstf = Xs;
  int sstride = 1;
  #pragma unroll
  for (int st = 0; st < 6; st++) {
    int jm = tid & ~(sstride - 1);
    float rev = (float)jm * (1.0f/4096.0f);
    float sn = __builtin_amdgcn_sinf(rev);
    float cs = __builtin_amdgcn_cosf(rev);
    c32 w1 = make_float2(cs, sn);
    c32 w2 = cmul(w1, w1);
    c32 w3 = cmul(w2, w1);
    c32 a = srcf[tid];
    c32 b = srcf[tid + 1024];
    c32 c = srcf[tid + 2048];
    c32 d = srcf[tid + 3072];
    c32 apc = cadd(a, c), amc = csub(a, c);
    c32 bpd = cadd(b, d), bmd = csub(b, d);
    int wb = tid + 3*jm;
    dstf[wb] = cadd(apc, bpd);
    dstf[wb + sstride]   = cmul(w1, make_float2(amc.x - bmd.y, amc.y + bmd.x));
    dstf[wb + 2*sstride] = cmul(w2, csub(apc, bpd));
    dstf[wb + 3*sstride] = cmul(w3, make_float2(amc.x + bmd.y, amc.y - bmd.x));
    __syncthreads();
    c32* t = srcf; srcf = dstf; dstf = t;
    sstride <<= 2;
  }

  // even stage count -> result in Zs (= srcf); z[m] = (x[2m], x[2m+1])
  {
    float4* o4 = (float4*)(out + (size_t)h*MF);
    const float4* s4 = (const float4*)srcf;
    o4[tid] = s4[tid];
    o4[tid + 1024] = s4[tid + 1024];
  }
}

extern "C" void kernel_launch(void* const* d_in, const int* in_sizes, int n_in,
                              void* d_out, int out_size, void* d_ws, size_t ws_size,
                              hipStream_t stream) {
  const float* log_dt = (const float*)d_in[0];
  const float* invwr  = (const float*)d_in[1];
  const float* wimag  = (const float*)d_in[2];
  const float* P      = (const float*)d_in[3];
  const float* B      = (const float*)d_in[4];
  const float* C      = (const float*)d_in[5];
  float* Sws = (float*)d_ws;                 // 1024 blocks * 64 floats = 256 KB
  c32*   out = (c32*)d_out;                  // (H,8192) fp32 = (H,4096) c32
  (void)in_sizes; (void)n_in; (void)out_size; (void)ws_size;

  ssk_S<<<4*HH, 512, 0, stream>>>(log_dt, invwr, wimag, P, C, Sws);
  ssk_B<<<HH, 1024, 0, stream>>>(log_dt, invwr, wimag, P, B, C, Sws, out);
}

// Round 14
// 64.798 us; speedup vs baseline: 1.7066x; 1.1202x over previous
//
#include <hip/hip_runtime.h>

// SSKernelNPLR, 2-kernel pipeline. H=256, N=32 (M=64 conj-extended), R=1, L=8192.
// K1 ssk_S (grid 1024, 512 thr, launch_bounds(512,4) -> VGPR cap 64):
//    contour with 4-lane (quad) node groups, 8 state-pairs/lane.
//    Loop1 per node: product-form iw = 1/[(z-d)(z-conj d)] stored (2 reg/state);
//    a,b accumulated via pair-fold numerators (alpha*z - beta)*iw.
//    Quad shfl_xor(1,2) reduce -> (a_j,b_j); q_j = z a/(1+b).
//    Loop2 (real-part deferral): U1x += Re(q iw), U2x += Re((qz) iw) — only the
//    real parts are ever consumed; per-state constants applied once at the end:
//    ssx = 2 U2x - 2Re(d) U1x, ssy = 2Im(d) U1x.  (verified == r13 form)
//    8 node-iters/thread. Reduce: masked butterfly (xor 4..32) -> LDS ->
//    64-thread cross-wave sum -> Sws [h][part][2m+bit].
// K2 ssk_B (grid 256, 1024 thr): combine + C~ + poly-form Cauchy at
//    z = 2i tan(pi j/L); Woodbury + (1+iT); real-irfft packing; 6-stage
//    radix-4 Stockham inverse FFT -> out.  (r13-verified, unchanged)

#define HH 256
#define NN 32
#define MF 4096

typedef float2 c32;

__device__ __forceinline__ c32 cmul(c32 a, c32 b){ return make_float2(a.x*b.x - a.y*b.y, a.x*b.y + a.y*b.x); }
__device__ __forceinline__ c32 cadd(c32 a, c32 b){ return make_float2(a.x+b.x, a.y+b.y); }
__device__ __forceinline__ c32 csub(c32 a, c32 b){ return make_float2(a.x-b.x, a.y-b.y); }
__device__ __forceinline__ c32 cconjf(c32 a){ return make_float2(a.x, -a.y); }
__device__ __forceinline__ float frcp(float x){ return __builtin_amdgcn_rcpf(x); }

// ---------------- K1: contour, quad node groups, real-part-deferred S ------
__global__ __launch_bounds__(512, 4)
void ssk_S(const float* __restrict__ log_dt, const float* __restrict__ invwr,
           const float* __restrict__ wim, const float* __restrict__ Pin,
           const float* __restrict__ Cin, float* __restrict__ Sws)
{
  // padded index pm = m + (m>>3) -> quad lanes hit distinct bank groups
  __shared__ __align__(16) float4 tA[36];   // (d.x, d.y, alpha_a, beta_a)
  __shared__ c32 tB[36];                    // (alpha_b, beta_b)
  __shared__ c32 tC[36];                    // (2Re d, 2Im d)
  __shared__ float red[8*64];               // [wave][component]
  const int bid = blockIdx.x;
  const int h = bid >> 2;
  const int base = (bid & 3) << 10;         // 0,1024,2048,3072
  const int tid = threadIdx.x;

  // ---- A1: per-head algebra (wave 0; m = tid, conj half for m>=32) ----
  if (tid < 64) {
    const int n = tid & 31;
    const bool cj = tid >= 32;
    const float dt = expf(log_dt[h]);
    float wr = -expf(invwr[h*NN + n]);
    float wi = wim[h*NN + n];
    if (cj) wi = -wi;
    const float tdt = 2.0f / dt;
    float dr = tdt - wr, di = -wi;
    float invd = 1.0f / (dr*dr + di*di);
    c32 D = make_float2(dr*invd, -di*invd);   // 1/(2/dt - w)
    c32 E = make_float2(tdt + wr, wi);        // 2/dt + w
    c32 Pf = make_float2(Pin[(h*NN+n)*2], Pin[(h*NN+n)*2+1]);
    if (cj) Pf.y = -Pf.y;
    c32 Cf = make_float2(Cin[(h*NN+n)*2], Cin[(h*NN+n)*2+1]);
    if (cj) Cf.y = -Cf.y;
    float rm = (Pf.x*Pf.x + Pf.y*Pf.y) * D.x; // Rm = 1 + sum |Pf|^2 Re(D)
    #pragma unroll
    for (int off = 32; off >= 1; off >>= 1) rm += __shfl_xor(rm, off, 64);
    rm += 1.0f;
    c32 Rc = cmul(cconjf(Pf), D);
    float invrm = 1.0f / rm;
    Rc.x *= invrm; Rc.y *= invrm;
    c32 RP = cmul(Rc, Pf);
    #pragma unroll
    for (int off = 32; off >= 1; off >>= 1) {
      RP.x += __shfl_xor(RP.x, off, 64);
      RP.y += __shfl_xor(RP.y, off, 64);
    }
    c32 Q2 = cconjf(Pf);
    c32 s  = csub(cmul(Rc, E), cmul(RP, Q2));
    c32 u  = cadd(Q2, s);                     // dA = diag(dd) - pp u^T
    c32 dd = cmul(D, E);
    c32 pp = cmul(D, Pf);
    c32 pc = cmul(pp, Cf);
    c32 pu = cmul(pp, u);
    if (tid < 32) {
      const int pm = tid + (tid >> 3);
      float ba = 2.0f*(pc.x*dd.x + pc.y*dd.y);
      float bb = 2.0f*(pu.x*dd.x + pu.y*dd.y);
      tA[pm] = make_float4(dd.x, dd.y, pc.x + pc.x, ba);
      tB[pm] = make_float2(pu.x + pu.x, bb);
      tC[pm] = make_float2(dd.x + dd.x, dd.y + dd.y);
    }
  }
  __syncthreads();

  const int sub = tid & 3;                    // 8-state slice
  const int grp = tid >> 2;                   // node slot 0..127
  const int pbase = sub * 9;                  // padded param base

  float U1x[8], U2x[8];                       // Sum Re(q iw), Sum Re((qz) iw)
  #pragma unroll
  for (int k = 0; k < 8; k++) { U1x[k] = 0.0f; U2x[k] = 0.0f; }

  for (int it = 0; it < 8; it++) {
    const int j = base + (it << 7) + grp;     // node index 0..4095
    float rev = (float)j * (1.0f/8192.0f);
    float zx = __builtin_amdgcn_cosf(rev);
    float zy = __builtin_amdgcn_sinf(rev);
    float t2zy = zy + zy;

    float iwxA[8], iwyA[8];
    float ax = 0.0f, ay = 0.0f, bx = 0.0f, by = 0.0f;
    #pragma unroll
    for (int k = 0; k < 8; k++) {
      float4 A = tA[pbase + k];               // d.x, d.y, aa, ba
      c32 Bv = tB[pbase + k];                 // ab, bb
      float dxx = zx - A.x;
      float dy1 = zy - A.y;
      float dy2 = zy + A.y;
      float xx  = dxx*dxx;
      float n1  = fmaf(dy1, dy1, xx);
      float n2  = fmaf(dy2, dy2, xx);
      float ip  = frcp(n1*n2);
      float p12 = dy1*dy2;
      float wvx = xx - p12;                   // Re[(z-d)(z-conj d)]
      float wvyn = dxx*t2zy;                  // Im[...] = dxx*(dy1+dy2)
      float iwx = wvx*ip;
      float iwy = -wvyn*ip;
      iwxA[k] = iwx; iwyA[k] = iwy;
      // a += (aa*z - ba)*iw ; b += (ab*z - bb)*iw
      float nax = fmaf(A.z, zx, -A.w);
      float nay = A.z*zy;
      ax = fmaf(nax, iwx, fmaf(-nay, iwy, ax));
      ay = fmaf(nax, iwy, fmaf( nay, iwx, ay));
      float nbx = fmaf(Bv.x, zx, -Bv.y);
      float nby = Bv.x*zy;
      bx = fmaf(nbx, iwx, fmaf(-nby, iwy, bx));
      by = fmaf(nbx, iwy, fmaf( nby, iwx, by));
    }
    // quad reduce: lanes of the 4-group hold disjoint state slices
    ax += __shfl_xor(ax, 1, 64); ax += __shfl_xor(ax, 2, 64);
    ay += __shfl_xor(ay, 1, 64); ay += __shfl_xor(ay, 2, 64);
    bx += __shfl_xor(bx, 1, 64); bx += __shfl_xor(bx, 2, 64);
    by += __shfl_xor(by, 1, 64); by += __shfl_xor(by, 2, 64);
    // q = z a/(1+b)  (quad-redundant)
    float denx = 1.0f + bx, deny = by;
    float idn = frcp(fmaf(denx, denx, deny*deny));
    float tx = (ax*denx + ay*deny)*idn;
    float ty = (ay*denx - ax*deny)*idn;
    float qx = zx*tx - zy*ty;
    float qy = zx*ty + zy*tx;
    if (j == 0) { qx *= 0.5f; qy *= 0.5f; }   // self-conj node z=1
    // qz = q*z (per node)
    float qzx = qx*zx - qy*zy;
    float qzy = fmaf(qx, zy, qy*zx);
    #pragma unroll
    for (int k = 0; k < 8; k++) {
      float iwx = iwxA[k], iwy = iwyA[k];
      U1x[k] = fmaf(qx,  iwx, fmaf(-qy,  iwy, U1x[k]));   // Re(q iw)
      U2x[k] = fmaf(qzx, iwx, fmaf(-qzy, iwy, U2x[k]));   // Re((qz) iw)
    }
  }

  // ---- apply per-state constants once: ssx = 2 U2x - 2Red U1x; ssy = 2Imd U1x
  float ssx[8], ssy[8];
  #pragma unroll
  for (int k = 0; k < 8; k++) {
    c32 Cv = tC[pbase + k];                   // (2Re d, 2Im d)
    ssx[k] = fmaf(-Cv.x, U1x[k], U2x[k] + U2x[k]);
    ssy[k] = Cv.y * U1x[k];
  }

  // ---- masked wave butterfly: combine lanes with the same sub ----
  #pragma unroll
  for (int off = 4; off <= 32; off <<= 1) {
    #pragma unroll
    for (int k = 0; k < 8; k++) {
      ssx[k] += __shfl_xor(ssx[k], off, 64);
      ssy[k] += __shfl_xor(ssy[k], off, 64);
    }
  }
  const int lane = tid & 63;
  const int wv = tid >> 6;
  if (lane < 4) {   // sub == lane here
    #pragma unroll
    for (int k = 0; k < 8; k++) {
      red[wv*64 + lane*16 + 2*k]     = ssx[k];  // component c = 2m+bit, m=lane*8+k
      red[wv*64 + lane*16 + 2*k + 1] = ssy[k];
    }
  }
  __syncthreads();

  if (tid < 64) {
    float t = 0.0f;
    #pragma unroll
    for (int w = 0; w < 8; w++) t += red[w*64 + tid];
    Sws[bid*64 + tid] = t;    // layout: [h][part][2m+bit]
  }
}

// ---------------- K2: combine + poly-Cauchy/Woodbury + irfft --------------
__global__ __launch_bounds__(1024, 4)
void ssk_B(const float* __restrict__ log_dt, const float* __restrict__ invwr,
           const float* __restrict__ wim, const float* __restrict__ Pin,
           const float* __restrict__ Bin, const float* __restrict__ Cin,
           const float* __restrict__ Sws, c32* __restrict__ out)
{
  __shared__ __align__(16) c32 Xs[4098];   // spectrum / FFT ping
  __shared__ __align__(16) c32 Zs[4096];   // packed seq / FFT pong
  __shared__ __align__(16) float4 cs1_s[NN];  // (aw, tnw, a00, b00)
  __shared__ __align__(16) float4 cs2_s[NN];  // (a01, b01, a10, b10)
  __shared__ c32 cs3_s[NN];                   // (a11, b11)
  const int h = blockIdx.x;
  const int tid = threadIdx.x;

  // ---- per-head algebra redo + combine (wave 0) ----
  if (tid < 64) {
    const int n = tid & 31;
    const bool cj = tid >= 32;
    const float dt = expf(log_dt[h]);
    float wr = -expf(invwr[h*NN + n]);
    float wi = wim[h*NN + n];
    if (cj) wi = -wi;
    const float tdt = 2.0f / dt;
    float dr = tdt - wr, di = -wi;
    float invd = 1.0f / (dr*dr + di*di);
    c32 D = make_float2(dr*invd, -di*invd);
    c32 E = make_float2(tdt + wr, wi);
    c32 Pf = make_float2(Pin[(h*NN+n)*2], Pin[(h*NN+n)*2+1]);
    if (cj) Pf.y = -Pf.y;
    c32 Cf = make_float2(Cin[(h*NN+n)*2], Cin[(h*NN+n)*2+1]);
    if (cj) Cf.y = -Cf.y;
    float rm = (Pf.x*Pf.x + Pf.y*Pf.y) * D.x;
    #pragma unroll
    for (int off = 32; off >= 1; off >>= 1) rm += __shfl_xor(rm, off, 64);
    rm += 1.0f;
    c32 Rc = cmul(cconjf(Pf), D);
    float invrm = 1.0f / rm;
    Rc.x *= invrm; Rc.y *= invrm;
    c32 RP = cmul(Rc, Pf);
    #pragma unroll
    for (int off = 32; off >= 1; off >>= 1) {
      RP.x += __shfl_xor(RP.x, off, 64);
      RP.y += __shfl_xor(RP.y, off, 64);
    }
    c32 Q2 = cconjf(Pf);
    c32 s  = csub(cmul(Rc, E), cmul(RP, Q2));
    c32 u  = cadd(Q2, s);
    c32 dd = cmul(D, E);
    c32 pp = cmul(D, Pf);
    c32 pc = cmul(pp, Cf);
    c32 pu = cmul(pp, u);

    // z = -1 node: g = conj(-1-d)/|.|^2 ; a,b real (conj-pair fold)
    float dxxn = -1.0f - dd.x;
    float nn1 = fmaf(dxxn, dxxn, dd.y*dd.y);
    float ii = frcp(nn1);
    float glxn = dxxn*ii, glyn = dd.y*ii;
    float aterm = 2.0f*(pc.x*glxn - pc.y*glyn);
    float bterm = 2.0f*(pu.x*glxn - pu.y*glyn);
    #pragma unroll
    for (int off = 16; off >= 1; off >>= 1) {
      aterm += __shfl_xor(aterm, off, 64);
      bterm += __shfl_xor(bterm, off, 64);
    }

    if (tid < 32) {
      const int m = tid;
      // exact diagonal part d^8192
      c32 dL = dd;
      #pragma unroll
      for (int i2 = 0; i2 < 13; i2++) dL = cmul(dL, dL);
      // total S: 4 partials + z=-1 node (q real, half weight)
      c32 S;
      S.x = (Sws[h*256 + 2*m]       + Sws[h*256 + 64 + 2*m])
          + (Sws[h*256 + 128 + 2*m] + Sws[h*256 + 192 + 2*m]);
      S.y = (Sws[h*256 + 2*m + 1]       + Sws[h*256 + 64 + 2*m + 1])
          + (Sws[h*256 + 128 + 2*m + 1] + Sws[h*256 + 192 + 2*m + 1]);
      float qn = -aterm * frcp(1.0f + bterm) * 0.5f;
      S.x += qn * 2.0f * glxn;
      S.y += qn * 2.0f * glyn;
      // C~ = C - (C dL - u S / 8192)
      c32 y = cmul(Cf, dL);
      c32 uS = cmul(u, S);
      y.x -= uS.x * (1.0f/8192.0f);
      y.y -= uS.y * (1.0f/8192.0f);
      c32 Ct = csub(Cf, y);
      // stage-B tables (poly-Cauchy constants), all dt-scaled
      c32 Bc = make_float2(Bin[(h*NN+m)*2], Bin[(h*NN+m)*2+1]);
      c32 Qc = cconjf(Pf);    // lane<32: Pf unconjugated
      c32 v00 = cmul(Bc, Ct), v01 = cmul(Bc, Qc), v10 = cmul(Pf, Ct), v11 = cmul(Pf, Qc);
      float wx = wr*dt, wy = wi*dt;
      float aw = fmaf(wx, wx, wy*wy);
      float tnw = -(wx + wx);
      float td = dt + dt;
      float a00 = td*v00.x, b00 = td*(v00.x*wx + v00.y*wy);
      float a01 = td*v01.x, b01 = td*(v01.x*wx + v01.y*wy);
      float a10 = td*v10.x, b10 = td*(v10.x*wx + v10.y*wy);
      float a11 = td*v11.x, b11 = td*(v11.x*wx + v11.y*wy);
      cs1_s[m] = make_float4(aw, tnw, a00, b00);
      cs2_s[m] = make_float4(a01, b01, a10, b10);
      cs3_s[m] = make_float2(a11, b11);
      // Nyquist X[4096] = sum Re(v00*dt)
      float s00 = v00.x * dt;
      #pragma unroll
      for (int off = 16; off >= 1; off >>= 1) s00 += __shfl_xor(s00, off, 64);
      if (m == 0) Xs[MF] = make_float2(s00, 0.0f);
    }
  }
  __syncthreads();

  // ---- poly Cauchy at z_j = 2i tan(pi j/L), 4 nodes/thread ----
  {
    float Tq[4], t2[4], t2sq[4];
    c32 a00[4], a01[4], a10[4], a11[4];
    #pragma unroll
    for (int q = 0; q < 4; q++) {
      int j = tid + (q << 10);
      float rev = (float)j * (1.0f/16384.0f);
      float sn = __builtin_amdgcn_sinf(rev);
      float cs = __builtin_amdgcn_cosf(rev);
      float T = sn * frcp(cs);
      Tq[q] = T; t2[q] = 2.0f*T; t2sq[q] = t2[q]*t2[q];
      a00[q] = make_float2(0,0); a01[q] = make_float2(0,0);
      a10[q] = make_float2(0,0); a11[q] = make_float2(0,0);
    }
    #pragma unroll 2
    for (int n = 0; n < NN; n++) {
      float4 C1 = cs1_s[n];   // aw, tnw, a00, b00
      float4 C2 = cs2_s[n];   // a01, b01, a10, b10
      c32   C3 = cs3_s[n];    // a11, b11
      #pragma unroll
      for (int q = 0; q < 4; q++) {
        float wvx = C1.x - t2sq[q];
        float wvy = C1.y * t2[q];
        float r = frcp(fmaf(wvx, wvx, wvy*wvy));
        float iwx = wvx*r;
        float iwy = -wvy*r;
        // acc += (-beta + i alpha t2) * iw, per vector
        float at;
        at = C1.z*t2[q];
        a00[q].x = fmaf(-C1.w, iwx, fmaf(-at, iwy, a00[q].x));
        a00[q].y = fmaf(-C1.w, iwy, fmaf( at, iwx, a00[q].y));
        at = C2.x*t2[q];
        a01[q].x = fmaf(-C2.y, iwx, fmaf(-at, iwy, a01[q].x));
        a01[q].y = fmaf(-C2.y, iwy, fmaf( at, iwx, a01[q].y));
        at = C2.z*t2[q];
        a10[q].x = fmaf(-C2.w, iwx, fmaf(-at, iwy, a10[q].x));
        a10[q].y = fmaf(-C2.w, iwy, fmaf( at, iwx, a10[q].y));
        at = C3.x*t2[q];
        a11[q].x = fmaf(-C3.y, iwx, fmaf(-at, iwy, a11[q].x));
        a11[q].y = fmaf(-C3.y, iwy, fmaf( at, iwx, a11[q].y));
      }
    }
    #pragma unroll
    for (int q = 0; q < 4; q++) {
      float denx = 1.0f + a11[q].x, deny = a11[q].y;
      float idn = frcp(fmaf(denx, denx, deny*deny));
      c32 invden = make_float2(denx*idn, -deny*idn);
      c32 kf = csub(a00[q], cmul(cmul(a01[q], a10[q]), invden));
      float T = Tq[q];
      Xs[tid + (q << 10)] = make_float2(kf.x - T*kf.y, kf.y + T*kf.x);  // *(1+iT)
    }
  }
  __syncthreads();

  // ---- real-irfft packing: Z[k] = (E[k] + i*O[k]) / MF ----
  const float invM = 1.0f / (float)MF;
  #pragma unroll
  for (int qq = 0; qq < 4; qq++) {
    int k = tid + (qq << 10);
    c32 Xk = Xs[k];
    c32 Xm = Xs[MF - k];
    float Ex = 0.5f*(Xk.x + Xm.x), Ey = 0.5f*(Xk.y - Xm.y);
    float Ox = 0.5f*(Xk.x - Xm.x), Oy = 0.5f*(Xk.y + Xm.y);
    float rev = (float)k * (1.0f/8192.0f);
    float cs = __builtin_amdgcn_cosf(rev);
    float sn = __builtin_amdgcn_sinf(rev);
    float Orx = Ox*cs - Oy*sn;
    float Ory = Ox*sn + Oy*cs;
    Zs[k] = make_float2((Ex - Ory)*invM, (Ey + Orx)*invM);
  }
  __syncthreads();

  // ---- 6-stage radix-4 Stockham inverse FFT (twiddle sign +) ----
  c32* srcf = Zs;
  c32* dstf = Xs;
  int sstride = 1;
  #pragma unroll
  for (int st = 0; st < 6; st++) {
    int jm = tid & ~(sstride - 1);
    float rev = (float)jm * (1.0f/4096.0f);
    float sn = __builtin_amdgcn_sinf(rev);
    float cs = __builtin_amdgcn_cosf(rev);
    c32 w1 = make_float2(cs, sn);
    c32 w2 = cmul(w1, w1);
    c32 w3 = cmul(w2, w1);
    c32 a = srcf[tid];
    c32 b = srcf[tid + 1024];
    c32 c = srcf[tid + 2048];
    c32 d = srcf[tid + 3072];
    c32 apc = cadd(a, c), amc = csub(a, c);
    c32 bpd = cadd(b, d), bmd = csub(b, d);
    int wb = tid + 3*jm;
    dstf[wb] = cadd(apc, bpd);
    dstf[wb + sstride]   = cmul(w1, make_float2(amc.x - bmd.y, amc.y + bmd.x));
    dstf[wb + 2*sstride] = cmul(w2, csub(apc, bpd));
    dstf[wb + 3*sstride] = cmul(w3, make_float2(amc.x + bmd.y, amc.y - bmd.x));
    __syncthreads();
    c32* t = srcf; srcf = dstf; dstf = t;
    sstride <<= 2;
  }

  // even stage count -> result in Zs (= srcf); z[m] = (x[2m], x[2m+1])
  {
    float4* o4 = (float4*)(out + (size_t)h*MF);
    const float4* s4 = (const float4*)srcf;
    o4[tid] = s4[tid];
    o4[tid + 1024] = s4[tid + 1024];
  }
}

extern "C" void kernel_launch(void* const* d_in, const int* in_sizes, int n_in,
                              void* d_out, int out_size, void* d_ws, size_t ws_size,
                              hipStream_t stream) {
  const float* log_dt = (const float*)d_in[0];
  const float* invwr  = (const float*)d_in[1];
  const float* wimag  = (const float*)d_in[2];
  const float* P      = (const float*)d_in[3];
  const float* B      = (const float*)d_in[4];
  const float* C      = (const float*)d_in[5];
  float* Sws = (float*)d_ws;                 // 1024 blocks * 64 floats = 256 KB
  c32*   out = (c32*)d_out;                  // (H,8192) fp32 = (H,4096) c32
  (void)in_sizes; (void)n_in; (void)out_size; (void)ws_size;

  ssk_S<<<4*HH, 512, 0, stream>>>(log_dt, invwr, wimag, P, C, Sws);
  ssk_B<<<HH, 1024, 0, stream>>>(log_dt, invwr, wimag, P, B, C, Sws, out);
}

// Round 15
// 61.566 us; speedup vs baseline: 1.7962x; 1.0525x over previous
//
#include <hip/hip_runtime.h>

// SSKernelNPLR, 2-kernel pipeline. H=256, N=32 (M=64 conj-extended), R=1, L=8192.
// K1 ssk_S (grid 1024, 512 thr, launch_bounds(512,2) -> VGPR cap 128):
//    contour with 4-lane (quad) node groups, 8 state-pairs/lane, ALL params
//    hoisted to registers (48 floats) -> zero DS reads in the hot loop.
//    Loop1 per node: product-form iw = 1/[(z-d)(z-conj d)] stored (2 reg/state);
//    a,b via DEFERRED form a = z*Sum(aa iw) - Sum(ba iw) (8 fma/state, exact
//    reassociation). Quad reduce via DPP quad_perm (xor1=0xB1, xor2=0x4E) on
//    the VALU pipe; q_j = z a/(1+b); loop2: U1 += Re(q iw), U2 += Re((qz) iw);
//    finals ssx = 2U2 - 2Re(d) U1, ssy = 2Im(d) U1 (r14-verified identity).
//    8 node-iters/thread. Butterfly (xor 4..32) -> LDS -> 64-thread cross-wave
//    sum -> Sws [h][part][2m+bit].
// K2 ssk_B (grid 256, 1024 thr): combine + C~ + poly-form Cauchy at
//    z = 2i tan(pi j/L); Woodbury + (1+iT); real-irfft packing; 6-stage
//    radix-4 Stockham inverse FFT -> out.  (r13/r14-verified, unchanged)

#define HH 256
#define NN 32
#define MF 4096

typedef float2 c32;

__device__ __forceinline__ c32 cmul(c32 a, c32 b){ return make_float2(a.x*b.x - a.y*b.y, a.x*b.y + a.y*b.x); }
__device__ __forceinline__ c32 cadd(c32 a, c32 b){ return make_float2(a.x+b.x, a.y+b.y); }
__device__ __forceinline__ c32 csub(c32 a, c32 b){ return make_float2(a.x-b.x, a.y-b.y); }
__device__ __forceinline__ c32 cconjf(c32 a){ return make_float2(a.x, -a.y); }
__device__ __forceinline__ float frcp(float x){ return __builtin_amdgcn_rcpf(x); }

// DPP quad_perm lane swaps (VALU pipe, no LDS): xor1 = [1,0,3,2], xor2 = [2,3,0,1]
__device__ __forceinline__ float dpp_xor1(float x){
  return __int_as_float(__builtin_amdgcn_update_dpp(0, __float_as_int(x), 0xB1, 0xF, 0xF, true));
}
__device__ __forceinline__ float dpp_xor2(float x){
  return __int_as_float(__builtin_amdgcn_update_dpp(0, __float_as_int(x), 0x4E, 0xF, 0xF, true));
}

// ---------------- K1: contour, quad groups, register-resident params -------
__global__ __launch_bounds__(512, 2)
void ssk_S(const float* __restrict__ log_dt, const float* __restrict__ invwr,
           const float* __restrict__ wim, const float* __restrict__ Pin,
           const float* __restrict__ Cin, float* __restrict__ Sws)
{
  __shared__ __align__(16) float4 tA[36];   // (d.x, d.y, alpha_a, beta_a), pad m+(m>>3)
  __shared__ c32 tB[36];                    // (alpha_b, beta_b)
  __shared__ float red[8*64];               // [wave][component]
  const int bid = blockIdx.x;
  const int h = bid >> 2;
  const int base = (bid & 3) << 10;         // 0,1024,2048,3072
  const int tid = threadIdx.x;

  // ---- A1: per-head algebra (wave 0; m = tid, conj half for m>=32) ----
  if (tid < 64) {
    const int n = tid & 31;
    const bool cj = tid >= 32;
    const float dt = expf(log_dt[h]);
    float wr = -expf(invwr[h*NN + n]);
    float wi = wim[h*NN + n];
    if (cj) wi = -wi;
    const float tdt = 2.0f / dt;
    float dr = tdt - wr, di = -wi;
    float invd = 1.0f / (dr*dr + di*di);
    c32 D = make_float2(dr*invd, -di*invd);   // 1/(2/dt - w)
    c32 E = make_float2(tdt + wr, wi);        // 2/dt + w
    c32 Pf = make_float2(Pin[(h*NN+n)*2], Pin[(h*NN+n)*2+1]);
    if (cj) Pf.y = -Pf.y;
    c32 Cf = make_float2(Cin[(h*NN+n)*2], Cin[(h*NN+n)*2+1]);
    if (cj) Cf.y = -Cf.y;
    float rm = (Pf.x*Pf.x + Pf.y*Pf.y) * D.x; // Rm = 1 + sum |Pf|^2 Re(D)
    #pragma unroll
    for (int off = 32; off >= 1; off >>= 1) rm += __shfl_xor(rm, off, 64);
    rm += 1.0f;
    c32 Rc = cmul(cconjf(Pf), D);
    float invrm = 1.0f / rm;
    Rc.x *= invrm; Rc.y *= invrm;
    c32 RP = cmul(Rc, Pf);
    #pragma unroll
    for (int off = 32; off >= 1; off >>= 1) {
      RP.x += __shfl_xor(RP.x, off, 64);
      RP.y += __shfl_xor(RP.y, off, 64);
    }
    c32 Q2 = cconjf(Pf);
    c32 s  = csub(cmul(Rc, E), cmul(RP, Q2));
    c32 u  = cadd(Q2, s);                     // dA = diag(dd) - pp u^T
    c32 dd = cmul(D, E);
    c32 pp = cmul(D, Pf);
    c32 pc = cmul(pp, Cf);
    c32 pu = cmul(pp, u);
    if (tid < 32) {
      const int pm = tid + (tid >> 3);
      float ba = 2.0f*(pc.x*dd.x + pc.y*dd.y);
      float bb = 2.0f*(pu.x*dd.x + pu.y*dd.y);
      tA[pm] = make_float4(dd.x, dd.y, pc.x + pc.x, ba);
      tB[pm] = make_float2(pu.x + pu.x, bb);
    }
  }
  __syncthreads();

  const int sub = tid & 3;                    // 8-state slice
  const int grp = tid >> 2;                   // node slot 0..127
  const int pbase = sub * 9;                  // padded param base

  // hoist all params to registers (loop-invariant)
  float pdx[8], pdy[8], paa[8], pba[8], pab[8], pbb[8];
  #pragma unroll
  for (int k = 0; k < 8; k++) {
    float4 A = tA[pbase + k];
    c32 Bv = tB[pbase + k];
    pdx[k] = A.x; pdy[k] = A.y; paa[k] = A.z; pba[k] = A.w;
    pab[k] = Bv.x; pbb[k] = Bv.y;
  }

  float U1x[8], U2x[8];                       // Sum Re(q iw), Sum Re((qz) iw)
  #pragma unroll
  for (int k = 0; k < 8; k++) { U1x[k] = 0.0f; U2x[k] = 0.0f; }

  for (int it = 0; it < 8; it++) {
    const int j = base + (it << 7) + grp;     // node index 0..4095
    float rev = (float)j * (1.0f/8192.0f);
    float zx = __builtin_amdgcn_cosf(rev);
    float zy = __builtin_amdgcn_sinf(rev);
    float t2zy = zy + zy;

    float iwxA[8], iwyA[8];
    // deferred a,b accumulators: P = sum aa*iw, Q = sum ba*iw, R = sum ab*iw, S2 = sum bb*iw
    float Px = 0.0f, Py = 0.0f, Qx = 0.0f, Qy = 0.0f;
    float Rx = 0.0f, Ry = 0.0f, Sx = 0.0f, Sy = 0.0f;
    #pragma unroll
    for (int k = 0; k < 8; k++) {
      float dxx = zx - pdx[k];
      float dy1 = zy - pdy[k];
      float dy2 = zy + pdy[k];
      float xx  = dxx*dxx;
      float n1  = fmaf(dy1, dy1, xx);
      float n2  = fmaf(dy2, dy2, xx);
      float ip  = frcp(n1*n2);
      float p12 = dy1*dy2;
      float wvx = xx - p12;                   // Re[(z-d)(z-conj d)]
      float wvyn = dxx*t2zy;                  // Im[...]
      float iwx = wvx*ip;
      float iwy = -wvyn*ip;
      iwxA[k] = iwx; iwyA[k] = iwy;
      Px = fmaf(paa[k], iwx, Px); Py = fmaf(paa[k], iwy, Py);
      Qx = fmaf(pba[k], iwx, Qx); Qy = fmaf(pba[k], iwy, Qy);
      Rx = fmaf(pab[k], iwx, Rx); Ry = fmaf(pab[k], iwy, Ry);
      Sx = fmaf(pbb[k], iwx, Sx); Sy = fmaf(pbb[k], iwy, Sy);
    }
    // assemble a = z*P - Q ; b = z*R - S2  (per-lane partials over 8 states)
    float ax = fmaf(zx, Px, fmaf(-zy, Py, -Qx));
    float ay = fmaf(zx, Py, fmaf( zy, Px, -Qy));
    float bx = fmaf(zx, Rx, fmaf(-zy, Ry, -Sx));
    float by = fmaf(zx, Ry, fmaf( zy, Rx, -Sy));
    // quad reduce on VALU via DPP (lanes of the 4-group hold disjoint slices)
    ax += dpp_xor1(ax); ax += dpp_xor2(ax);
    ay += dpp_xor1(ay); ay += dpp_xor2(ay);
    bx += dpp_xor1(bx); bx += dpp_xor2(bx);
    by += dpp_xor1(by); by += dpp_xor2(by);
    // q = z a/(1+b)  (quad-redundant)
    float denx = 1.0f + bx, deny = by;
    float idn = frcp(fmaf(denx, denx, deny*deny));
    float tx = (ax*denx + ay*deny)*idn;
    float ty = (ay*denx - ax*deny)*idn;
    float qx = zx*tx - zy*ty;
    float qy = zx*ty + zy*tx;
    if (j == 0) { qx *= 0.5f; qy *= 0.5f; }   // self-conj node z=1
    // qz = q*z (per node)
    float qzx = qx*zx - qy*zy;
    float qzy = fmaf(qx, zy, qy*zx);
    #pragma unroll
    for (int k = 0; k < 8; k++) {
      float iwx = iwxA[k], iwy = iwyA[k];
      U1x[k] = fmaf(qx,  iwx, fmaf(-qy,  iwy, U1x[k]));   // Re(q iw)
      U2x[k] = fmaf(qzx, iwx, fmaf(-qzy, iwy, U2x[k]));   // Re((qz) iw)
    }
  }

  // ---- per-state finals: ssx = 2 U2x - 2Re(d) U1x ; ssy = 2Im(d) U1x ----
  float ssx[8], ssy[8];
  #pragma unroll
  for (int k = 0; k < 8; k++) {
    ssx[k] = fmaf(-(pdx[k] + pdx[k]), U1x[k], U2x[k] + U2x[k]);
    ssy[k] = (pdy[k] + pdy[k]) * U1x[k];
  }

  // ---- masked wave butterfly: combine lanes with the same sub ----
  #pragma unroll
  for (int off = 4; off <= 32; off <<= 1) {
    #pragma unroll
    for (int k = 0; k < 8; k++) {
      ssx[k] += __shfl_xor(ssx[k], off, 64);
      ssy[k] += __shfl_xor(ssy[k], off, 64);
    }
  }
  const int lane = tid & 63;
  const int wv = tid >> 6;
  if (lane < 4) {   // sub == lane here
    #pragma unroll
    for (int k = 0; k < 8; k++) {
      red[wv*64 + lane*16 + 2*k]     = ssx[k];  // component c = 2m+bit, m=lane*8+k
      red[wv*64 + lane*16 + 2*k + 1] = ssy[k];
    }
  }
  __syncthreads();

  if (tid < 64) {
    float t = 0.0f;
    #pragma unroll
    for (int w = 0; w < 8; w++) t += red[w*64 + tid];
    Sws[bid*64 + tid] = t;    // layout: [h][part][2m+bit]
  }
}

// ---------------- K2: combine + poly-Cauchy/Woodbury + irfft --------------
__global__ __launch_bounds__(1024, 4)
void ssk_B(const float* __restrict__ log_dt, const float* __restrict__ invwr,
           const float* __restrict__ wim, const float* __restrict__ Pin,
           const float* __restrict__ Bin, const float* __restrict__ Cin,
           const float* __restrict__ Sws, c32* __restrict__ out)
{
  __shared__ __align__(16) c32 Xs[4098];   // spectrum / FFT ping
  __shared__ __align__(16) c32 Zs[4096];   // packed seq / FFT pong
  __shared__ __align__(16) float4 cs1_s[NN];  // (aw, tnw, a00, b00)
  __shared__ __align__(16) float4 cs2_s[NN];  // (a01, b01, a10, b10)
  __shared__ c32 cs3_s[NN];                   // (a11, b11)
  const int h = blockIdx.x;
  const int tid = threadIdx.x;

  // ---- per-head algebra redo + combine (wave 0) ----
  if (tid < 64) {
    const int n = tid & 31;
    const bool cj = tid >= 32;
    const float dt = expf(log_dt[h]);
    float wr = -expf(invwr[h*NN + n]);
    float wi = wim[h*NN + n];
    if (cj) wi = -wi;
    const float tdt = 2.0f / dt;
    float dr = tdt - wr, di = -wi;
    float invd = 1.0f / (dr*dr + di*di);
    c32 D = make_float2(dr*invd, -di*invd);
    c32 E = make_float2(tdt + wr, wi);
    c32 Pf = make_float2(Pin[(h*NN+n)*2], Pin[(h*NN+n)*2+1]);
    if (cj) Pf.y = -Pf.y;
    c32 Cf = make_float2(Cin[(h*NN+n)*2], Cin[(h*NN+n)*2+1]);
    if (cj) Cf.y = -Cf.y;
    float rm = (Pf.x*Pf.x + Pf.y*Pf.y) * D.x;
    #pragma unroll
    for (int off = 32; off >= 1; off >>= 1) rm += __shfl_xor(rm, off, 64);
    rm += 1.0f;
    c32 Rc = cmul(cconjf(Pf), D);
    float invrm = 1.0f / rm;
    Rc.x *= invrm; Rc.y *= invrm;
    c32 RP = cmul(Rc, Pf);
    #pragma unroll
    for (int off = 32; off >= 1; off >>= 1) {
      RP.x += __shfl_xor(RP.x, off, 64);
      RP.y += __shfl_xor(RP.y, off, 64);
    }
    c32 Q2 = cconjf(Pf);
    c32 s  = csub(cmul(Rc, E), cmul(RP, Q2));
    c32 u  = cadd(Q2, s);
    c32 dd = cmul(D, E);
    c32 pp = cmul(D, Pf);
    c32 pc = cmul(pp, Cf);
    c32 pu = cmul(pp, u);

    // z = -1 node: g = conj(-1-d)/|.|^2 ; a,b real (conj-pair fold)
    float dxxn = -1.0f - dd.x;
    float nn1 = fmaf(dxxn, dxxn, dd.y*dd.y);
    float ii = frcp(nn1);
    float glxn = dxxn*ii, glyn = dd.y*ii;
    float aterm = 2.0f*(pc.x*glxn - pc.y*glyn);
    float bterm = 2.0f*(pu.x*glxn - pu.y*glyn);
    #pragma unroll
    for (int off = 16; off >= 1; off >>= 1) {
      aterm += __shfl_xor(aterm, off, 64);
      bterm += __shfl_xor(bterm, off, 64);
    }

    if (tid < 32) {
      const int m = tid;
      // exact diagonal part d^8192
      c32 dL = dd;
      #pragma unroll
      for (int i2 = 0; i2 < 13; i2++) dL = cmul(dL, dL);
      // total S: 4 partials + z=-1 node (q real, half weight)
      c32 S;
      S.x = (Sws[h*256 + 2*m]       + Sws[h*256 + 64 + 2*m])
          + (Sws[h*256 + 128 + 2*m] + Sws[h*256 + 192 + 2*m]);
      S.y = (Sws[h*256 + 2*m + 1]       + Sws[h*256 + 64 + 2*m + 1])
          + (Sws[h*256 + 128 + 2*m + 1] + Sws[h*256 + 192 + 2*m + 1]);
      float qn = -aterm * frcp(1.0f + bterm) * 0.5f;
      S.x += qn * 2.0f * glxn;
      S.y += qn * 2.0f * glyn;
      // C~ = C - (C dL - u S / 8192)
      c32 y = cmul(Cf, dL);
      c32 uS = cmul(u, S);
      y.x -= uS.x * (1.0f/8192.0f);
      y.y -= uS.y * (1.0f/8192.0f);
      c32 Ct = csub(Cf, y);
      // stage-B tables (poly-Cauchy constants), all dt-scaled
      c32 Bc = make_float2(Bin[(h*NN+m)*2], Bin[(h*NN+m)*2+1]);
      c32 Qc = cconjf(Pf);    // lane<32: Pf unconjugated
      c32 v00 = cmul(Bc, Ct), v01 = cmul(Bc, Qc), v10 = cmul(Pf, Ct), v11 = cmul(Pf, Qc);
      float wx = wr*dt, wy = wi*dt;
      float aw = fmaf(wx, wx, wy*wy);
      float tnw = -(wx + wx);
      float td = dt + dt;
      float a00 = td*v00.x, b00 = td*(v00.x*wx + v00.y*wy);
      float a01 = td*v01.x, b01 = td*(v01.x*wx + v01.y*wy);
      float a10 = td*v10.x, b10 = td*(v10.x*wx + v10.y*wy);
      float a11 = td*v11.x, b11 = td*(v11.x*wx + v11.y*wy);
      cs1_s[m] = make_float4(aw, tnw, a00, b00);
      cs2_s[m] = make_float4(a01, b01, a10, b10);
      cs3_s[m] = make_float2(a11, b11);
      // Nyquist X[4096] = sum Re(v00*dt)
      float s00 = v00.x * dt;
      #pragma unroll
      for (int off = 16; off >= 1; off >>= 1) s00 += __shfl_xor(s00, off, 64);
      if (m == 0) Xs[MF] = make_float2(s00, 0.0f);
    }
  }
  __syncthreads();

  // ---- poly Cauchy at z_j = 2i tan(pi j/L), 4 nodes/thread ----
  {
    float Tq[4], t2[4], t2sq[4];
    c32 a00[4], a01[4], a10[4], a11[4];
    #pragma unroll
    for (int q = 0; q < 4; q++) {
      int j = tid + (q << 10);
      float rev = (float)j * (1.0f/16384.0f);
      float sn = __builtin_amdgcn_sinf(rev);
      float cs = __builtin_amdgcn_cosf(rev);
      float T = sn * frcp(cs);
      Tq[q] = T; t2[q] = 2.0f*T; t2sq[q] = t2[q]*t2[q];
      a00[q] = make_float2(0,0); a01[q] = make_float2(0,0);
      a10[q] = make_float2(0,0); a11[q] = make_float2(0,0);
    }
    #pragma unroll 2
    for (int n = 0; n < NN; n++) {
      float4 C1 = cs1_s[n];   // aw, tnw, a00, b00
      float4 C2 = cs2_s[n];   // a01, b01, a10, b10
      c32   C3 = cs3_s[n];    // a11, b11
      #pragma unroll
      for (int q = 0; q < 4; q++) {
        float wvx = C1.x - t2sq[q];
        float wvy = C1.y * t2[q];
        float r = frcp(fmaf(wvx, wvx, wvy*wvy));
        float iwx = wvx*r;
        float iwy = -wvy*r;
        // acc += (-beta + i alpha t2) * iw, per vector
        float at;
        at = C1.z*t2[q];
        a00[q].x = fmaf(-C1.w, iwx, fmaf(-at, iwy, a00[q].x));
        a00[q].y = fmaf(-C1.w, iwy, fmaf( at, iwx, a00[q].y));
        at = C2.x*t2[q];
        a01[q].x = fmaf(-C2.y, iwx, fmaf(-at, iwy, a01[q].x));
        a01[q].y = fmaf(-C2.y, iwy, fmaf( at, iwx, a01[q].y));
        at = C2.z*t2[q];
        a10[q].x = fmaf(-C2.w, iwx, fmaf(-at, iwy, a10[q].x));
        a10[q].y = fmaf(-C2.w, iwy, fmaf( at, iwx, a10[q].y));
        at = C3.x*t2[q];
        a11[q].x = fmaf(-C3.y, iwx, fmaf(-at, iwy, a11[q].x));
        a11[q].y = fmaf(-C3.y, iwy, fmaf( at, iwx, a11[q].y));
      }
    }
    #pragma unroll
    for (int q = 0; q < 4; q++) {
      float denx = 1.0f + a11[q].x, deny = a11[q].y;
      float idn = frcp(fmaf(denx, denx, deny*deny));
      c32 invden = make_float2(denx*idn, -deny*idn);
      c32 kf = csub(a00[q], cmul(cmul(a01[q], a10[q]), invden));
      float T = Tq[q];
      Xs[tid + (q << 10)] = make_float2(kf.x - T*kf.y, kf.y + T*kf.x);  // *(1+iT)
    }
  }
  __syncthreads();

  // ---- real-irfft packing: Z[k] = (E[k] + i*O[k]) / MF ----
  const float invM = 1.0f / (float)MF;
  #pragma unroll
  for (int qq = 0; qq < 4; qq++) {
    int k = tid + (qq << 10);
    c32 Xk = Xs[k];
    c32 Xm = Xs[MF - k];
    float Ex = 0.5f*(Xk.x + Xm.x), Ey = 0.5f*(Xk.y - Xm.y);
    float Ox = 0.5f*(Xk.x - Xm.x), Oy = 0.5f*(Xk.y + Xm.y);
    float rev = (float)k * (1.0f/8192.0f);
    float cs = __builtin_amdgcn_cosf(rev);
    float sn = __builtin_amdgcn_sinf(rev);
    float Orx = Ox*cs - Oy*sn;
    float Ory = Ox*sn + Oy*cs;
    Zs[k] = make_float2((Ex - Ory)*invM, (Ey + Orx)*invM);
  }
  __syncthreads();

  // ---- 6-stage radix-4 Stockham inverse FFT (twiddle sign +) ----
  c32* srcf = Zs;
  c32* dstf = Xs;
  int sstride = 1;
  #pragma unroll
  for (int st = 0; st < 6; st++) {
    int jm = tid & ~(sstride - 1);
    float rev = (float)jm * (1.0f/4096.0f);
    float sn = __builtin_amdgcn_sinf(rev);
    float cs = __builtin_amdgcn_cosf(rev);
    c32 w1 = make_float2(cs, sn);
    c32 w2 = cmul(w1, w1);
    c32 w3 = cmul(w2, w1);
    c32 a = srcf[tid];
    c32 b = srcf[tid + 1024];
    c32 c = srcf[tid + 2048];
    c32 d = srcf[tid + 3072];
    c32 apc = cadd(a, c), amc = csub(a, c);
    c32 bpd = cadd(b, d), bmd = csub(b, d);
    int wb = tid + 3*jm;
    dstf[wb] = cadd(apc, bpd);
    dstf[wb + sstride]   = cmul(w1, make_float2(amc.x - bmd.y, amc.y + bmd.x));
    dstf[wb + 2*sstride] = cmul(w2, csub(apc, bpd));
    dstf[wb + 3*sstride] = cmul(w3, make_float2(amc.x + bmd.y, amc.y - bmd.x));
    __syncthreads();
    c32* t = srcf; srcf = dstf; dstf = t;
    sstride <<= 2;
  }

  // even stage count -> result in Zs (= srcf); z[m] = (x[2m], x[2m+1])
  {
    float4* o4 = (float4*)(out + (size_t)h*MF);
    const float4* s4 = (const float4*)srcf;
    o4[tid] = s4[tid];
    o4[tid + 1024] = s4[tid + 1024];
  }
}

extern "C" void kernel_launch(void* const* d_in, const int* in_sizes, int n_in,
                              void* d_out, int out_size, void* d_ws, size_t ws_size,
                              hipStream_t stream) {
  const float* log_dt = (const float*)d_in[0];
  const float* invwr  = (const float*)d_in[1];
  const float* wimag  = (const float*)d_in[2];
  const float* P      = (const float*)d_in[3];
  const float* B      = (const float*)d_in[4];
  const float* C      = (const float*)d_in[5];
  float* Sws = (float*)d_ws;                 // 1024 blocks * 64 floats = 256 KB
  c32*   out = (c32*)d_out;                  // (H,8192) fp32 = (H,4096) c32
  (void)in_sizes; (void)n_in; (void)out_size; (void)ws_size;

  ssk_S<<<4*HH, 512, 0, stream>>>(log_dt, invwr, wimag, P, C, Sws);
  ssk_B<<<HH, 1024, 0, stream>>>(log_dt, invwr, wimag, P, B, C, Sws, out);
}

// Round 16
// 57.356 us; speedup vs baseline: 1.9281x; 1.0734x over previous
//
#include <hip/hip_runtime.h>

// SSKernelNPLR, 2-kernel pipeline. H=256, N=32 (M=64 conj-extended), R=1, L=8192.
// K1 ssk_S (grid 512, 512 thr, launch_bounds(512,2) -> VGPR cap 128):
//    contour with 4-lane (quad) node groups, 8 state-pairs/lane, ALL params
//    register-resident. 2 parts/h, 16 node-iters/thread -> all blocks
//    co-resident in ONE round (2 blocks/CU). Loop1 per node: product-form
//    iw = 1/[(z-d)(z-conj d)] with den = wvx^2 + wvyn^2 (== n1*n2);
//    a,b deferred: a = z*Sum(aa iw) - Sum(ba iw). Quad reduce via DPP
//    (xor1=0xB1, xor2=0x4E); q = z a/(1+b); U1 += Re(q iw), U2 += Re((qz) iw);
//    finals ssx = 2U2 - 2Re(d) U1, ssy = 2Im(d) U1. Butterfly (xor 4..32) ->
//    LDS -> 64-thread cross-wave sum -> Sws [h][half][2m+bit]  (r6 layout).
// K2 ssk_B (grid 256, 1024 thr): combine (2 halves) + C~ + poly-form Cauchy at
//    z = 2i tan(pi j/L); Woodbury + (1+iT); real-irfft packing; 6-stage
//    radix-4 Stockham inverse FFT -> out.  (r13-15-verified)

#define HH 256
#define NN 32
#define MF 4096

typedef float2 c32;

__device__ __forceinline__ c32 cmul(c32 a, c32 b){ return make_float2(a.x*b.x - a.y*b.y, a.x*b.y + a.y*b.x); }
__device__ __forceinline__ c32 cadd(c32 a, c32 b){ return make_float2(a.x+b.x, a.y+b.y); }
__device__ __forceinline__ c32 csub(c32 a, c32 b){ return make_float2(a.x-b.x, a.y-b.y); }
__device__ __forceinline__ c32 cconjf(c32 a){ return make_float2(a.x, -a.y); }
__device__ __forceinline__ float frcp(float x){ return __builtin_amdgcn_rcpf(x); }

// DPP quad_perm lane swaps (VALU pipe): xor1 = [1,0,3,2], xor2 = [2,3,0,1]
__device__ __forceinline__ float dpp_xor1(float x){
  return __int_as_float(__builtin_amdgcn_update_dpp(0, __float_as_int(x), 0xB1, 0xF, 0xF, true));
}
__device__ __forceinline__ float dpp_xor2(float x){
  return __int_as_float(__builtin_amdgcn_update_dpp(0, __float_as_int(x), 0x4E, 0xF, 0xF, true));
}

// ---------------- K1: contour, quad groups, single resident round ----------
__global__ __launch_bounds__(512, 2)
void ssk_S(const float* __restrict__ log_dt, const float* __restrict__ invwr,
           const float* __restrict__ wim, const float* __restrict__ Pin,
           const float* __restrict__ Cin, float* __restrict__ Sws)
{
  __shared__ __align__(16) float4 tA[36];   // (d.x, d.y, alpha_a, beta_a), pad m+(m>>3)
  __shared__ c32 tB[36];                    // (alpha_b, beta_b)
  __shared__ float red[8*64];               // [wave][component]
  const int bid = blockIdx.x;
  const int h = bid >> 1;
  const int base = (bid & 1) << 11;         // 0 or 2048
  const int tid = threadIdx.x;

  // ---- A1: per-head algebra (wave 0; m = tid, conj half for m>=32) ----
  if (tid < 64) {
    const int n = tid & 31;
    const bool cj = tid >= 32;
    const float dt = expf(log_dt[h]);
    float wr = -expf(invwr[h*NN + n]);
    float wi = wim[h*NN + n];
    if (cj) wi = -wi;
    const float tdt = 2.0f / dt;
    float dr = tdt - wr, di = -wi;
    float invd = 1.0f / (dr*dr + di*di);
    c32 D = make_float2(dr*invd, -di*invd);   // 1/(2/dt - w)
    c32 E = make_float2(tdt + wr, wi);        // 2/dt + w
    c32 Pf = make_float2(Pin[(h*NN+n)*2], Pin[(h*NN+n)*2+1]);
    if (cj) Pf.y = -Pf.y;
    c32 Cf = make_float2(Cin[(h*NN+n)*2], Cin[(h*NN+n)*2+1]);
    if (cj) Cf.y = -Cf.y;
    float rm = (Pf.x*Pf.x + Pf.y*Pf.y) * D.x; // Rm = 1 + sum |Pf|^2 Re(D)
    #pragma unroll
    for (int off = 32; off >= 1; off >>= 1) rm += __shfl_xor(rm, off, 64);
    rm += 1.0f;
    c32 Rc = cmul(cconjf(Pf), D);
    float invrm = 1.0f / rm;
    Rc.x *= invrm; Rc.y *= invrm;
    c32 RP = cmul(Rc, Pf);
    #pragma unroll
    for (int off = 32; off >= 1; off >>= 1) {
      RP.x += __shfl_xor(RP.x, off, 64);
      RP.y += __shfl_xor(RP.y, off, 64);
    }
    c32 Q2 = cconjf(Pf);
    c32 s  = csub(cmul(Rc, E), cmul(RP, Q2));
    c32 u  = cadd(Q2, s);                     // dA = diag(dd) - pp u^T
    c32 dd = cmul(D, E);
    c32 pp = cmul(D, Pf);
    c32 pc = cmul(pp, Cf);
    c32 pu = cmul(pp, u);
    if (tid < 32) {
      const int pm = tid + (tid >> 3);
      float ba = 2.0f*(pc.x*dd.x + pc.y*dd.y);
      float bb = 2.0f*(pu.x*dd.x + pu.y*dd.y);
      tA[pm] = make_float4(dd.x, dd.y, pc.x + pc.x, ba);
      tB[pm] = make_float2(pu.x + pu.x, bb);
    }
  }
  __syncthreads();

  const int sub = tid & 3;                    // 8-state slice
  const int grp = tid >> 2;                   // node slot 0..127
  const int pbase = sub * 9;                  // padded param base

  // hoist all params to registers (loop-invariant)
  float pdx[8], pdy[8], paa[8], pba[8], pab[8], pbb[8];
  #pragma unroll
  for (int k = 0; k < 8; k++) {
    float4 A = tA[pbase + k];
    c32 Bv = tB[pbase + k];
    pdx[k] = A.x; pdy[k] = A.y; paa[k] = A.z; pba[k] = A.w;
    pab[k] = Bv.x; pbb[k] = Bv.y;
  }

  float U1x[8], U2x[8];                       // Sum Re(q iw), Sum Re((qz) iw)
  #pragma unroll
  for (int k = 0; k < 8; k++) { U1x[k] = 0.0f; U2x[k] = 0.0f; }

  for (int it = 0; it < 16; it++) {
    const int j = base + (it << 7) + grp;     // node index 0..4095
    float rev = (float)j * (1.0f/8192.0f);
    float zx = __builtin_amdgcn_cosf(rev);
    float zy = __builtin_amdgcn_sinf(rev);
    float t2zy = zy + zy;

    float iwxA[8], iwyA[8];
    // deferred a,b accumulators: P = sum aa*iw, Q = sum ba*iw, R = sum ab*iw, S2 = sum bb*iw
    float Px = 0.0f, Py = 0.0f, Qx = 0.0f, Qy = 0.0f;
    float Rx = 0.0f, Ry = 0.0f, Sx = 0.0f, Sy = 0.0f;
    #pragma unroll
    for (int k = 0; k < 8; k++) {
      float dxx = zx - pdx[k];
      float dy1 = zy - pdy[k];
      float dy2 = zy + pdy[k];
      float xx  = dxx*dxx;
      float p12 = dy1*dy2;
      float wvx = xx - p12;                   // Re[(z-d)(z-conj d)]
      float wvyn = dxx*t2zy;                  // Im[...]
      float den = fmaf(wvx, wvx, wvyn*wvyn);  // == n1*n2 exactly (product form)
      float ip  = frcp(den);
      float iwx = wvx*ip;
      float iwy = -wvyn*ip;
      iwxA[k] = iwx; iwyA[k] = iwy;
      Px = fmaf(paa[k], iwx, Px); Py = fmaf(paa[k], iwy, Py);
      Qx = fmaf(pba[k], iwx, Qx); Qy = fmaf(pba[k], iwy, Qy);
      Rx = fmaf(pab[k], iwx, Rx); Ry = fmaf(pab[k], iwy, Ry);
      Sx = fmaf(pbb[k], iwx, Sx); Sy = fmaf(pbb[k], iwy, Sy);
    }
    // assemble a = z*P - Q ; b = z*R - S2  (per-lane partials over 8 states)
    float ax = fmaf(zx, Px, fmaf(-zy, Py, -Qx));
    float ay = fmaf(zx, Py, fmaf( zy, Px, -Qy));
    float bx = fmaf(zx, Rx, fmaf(-zy, Ry, -Sx));
    float by = fmaf(zx, Ry, fmaf( zy, Rx, -Sy));
    // quad reduce on VALU via DPP
    ax += dpp_xor1(ax); ax += dpp_xor2(ax);
    ay += dpp_xor1(ay); ay += dpp_xor2(ay);
    bx += dpp_xor1(bx); bx += dpp_xor2(bx);
    by += dpp_xor1(by); by += dpp_xor2(by);
    // q = z a/(1+b)  (quad-redundant)
    float denq = 1.0f + bx, deny = by;
    float idn = frcp(fmaf(denq, denq, deny*deny));
    float tx = (ax*denq + ay*deny)*idn;
    float ty = (ay*denq - ax*deny)*idn;
    float qx = zx*tx - zy*ty;
    float qy = zx*ty + zy*tx;
    if (j == 0) { qx *= 0.5f; qy *= 0.5f; }   // self-conj node z=1
    // qz = q*z (per node)
    float qzx = qx*zx - qy*zy;
    float qzy = fmaf(qx, zy, qy*zx);
    #pragma unroll
    for (int k = 0; k < 8; k++) {
      float iwx = iwxA[k], iwy = iwyA[k];
      U1x[k] = fmaf(qx,  iwx, fmaf(-qy,  iwy, U1x[k]));   // Re(q iw)
      U2x[k] = fmaf(qzx, iwx, fmaf(-qzy, iwy, U2x[k]));   // Re((qz) iw)
    }
  }

  // ---- per-state finals: ssx = 2 U2x - 2Re(d) U1x ; ssy = 2Im(d) U1x ----
  float ssx[8], ssy[8];
  #pragma unroll
  for (int k = 0; k < 8; k++) {
    ssx[k] = fmaf(-(pdx[k] + pdx[k]), U1x[k], U2x[k] + U2x[k]);
    ssy[k] = (pdy[k] + pdy[k]) * U1x[k];
  }

  // ---- masked wave butterfly: combine lanes with the same sub ----
  #pragma unroll
  for (int off = 4; off <= 32; off <<= 1) {
    #pragma unroll
    for (int k = 0; k < 8; k++) {
      ssx[k] += __shfl_xor(ssx[k], off, 64);
      ssy[k] += __shfl_xor(ssy[k], off, 64);
    }
  }
  const int lane = tid & 63;
  const int wv = tid >> 6;
  if (lane < 4) {   // sub == lane here
    #pragma unroll
    for (int k = 0; k < 8; k++) {
      red[wv*64 + lane*16 + 2*k]     = ssx[k];  // component c = 2m+bit, m=lane*8+k
      red[wv*64 + lane*16 + 2*k + 1] = ssy[k];
    }
  }
  __syncthreads();

  if (tid < 64) {
    float t = 0.0f;
    #pragma unroll
    for (int w = 0; w < 8; w++) t += red[w*64 + tid];
    Sws[bid*64 + tid] = t;    // layout: [h][half][2m+bit]
  }
}

// ---------------- K2: combine + poly-Cauchy/Woodbury + irfft --------------
__global__ __launch_bounds__(1024, 4)
void ssk_B(const float* __restrict__ log_dt, const float* __restrict__ invwr,
           const float* __restrict__ wim, const float* __restrict__ Pin,
           const float* __restrict__ Bin, const float* __restrict__ Cin,
           const float* __restrict__ Sws, c32* __restrict__ out)
{
  __shared__ __align__(16) c32 Xs[4098];   // spectrum / FFT ping
  __shared__ __align__(16) c32 Zs[4096];   // packed seq / FFT pong
  __shared__ __align__(16) float4 cs1_s[NN];  // (aw, tnw, a00, b00)
  __shared__ __align__(16) float4 cs2_s[NN];  // (a01, b01, a10, b10)
  __shared__ c32 cs3_s[NN];                   // (a11, b11)
  const int h = blockIdx.x;
  const int tid = threadIdx.x;

  // ---- per-head algebra redo + combine (wave 0) ----
  if (tid < 64) {
    const int n = tid & 31;
    const bool cj = tid >= 32;
    const float dt = expf(log_dt[h]);
    float wr = -expf(invwr[h*NN + n]);
    float wi = wim[h*NN + n];
    if (cj) wi = -wi;
    const float tdt = 2.0f / dt;
    float dr = tdt - wr, di = -wi;
    float invd = 1.0f / (dr*dr + di*di);
    c32 D = make_float2(dr*invd, -di*invd);
    c32 E = make_float2(tdt + wr, wi);
    c32 Pf = make_float2(Pin[(h*NN+n)*2], Pin[(h*NN+n)*2+1]);
    if (cj) Pf.y = -Pf.y;
    c32 Cf = make_float2(Cin[(h*NN+n)*2], Cin[(h*NN+n)*2+1]);
    if (cj) Cf.y = -Cf.y;
    float rm = (Pf.x*Pf.x + Pf.y*Pf.y) * D.x;
    #pragma unroll
    for (int off = 32; off >= 1; off >>= 1) rm += __shfl_xor(rm, off, 64);
    rm += 1.0f;
    c32 Rc = cmul(cconjf(Pf), D);
    float invrm = 1.0f / rm;
    Rc.x *= invrm; Rc.y *= invrm;
    c32 RP = cmul(Rc, Pf);
    #pragma unroll
    for (int off = 32; off >= 1; off >>= 1) {
      RP.x += __shfl_xor(RP.x, off, 64);
      RP.y += __shfl_xor(RP.y, off, 64);
    }
    c32 Q2 = cconjf(Pf);
    c32 s  = csub(cmul(Rc, E), cmul(RP, Q2));
    c32 u  = cadd(Q2, s);
    c32 dd = cmul(D, E);
    c32 pp = cmul(D, Pf);
    c32 pc = cmul(pp, Cf);
    c32 pu = cmul(pp, u);

    // z = -1 node: g = conj(-1-d)/|.|^2 ; a,b real (conj-pair fold)
    float dxxn = -1.0f - dd.x;
    float nn1 = fmaf(dxxn, dxxn, dd.y*dd.y);
    float ii = frcp(nn1);
    float glxn = dxxn*ii, glyn = dd.y*ii;
    float aterm = 2.0f*(pc.x*glxn - pc.y*glyn);
    float bterm = 2.0f*(pu.x*glxn - pu.y*glyn);
    #pragma unroll
    for (int off = 16; off >= 1; off >>= 1) {
      aterm += __shfl_xor(aterm, off, 64);
      bterm += __shfl_xor(bterm, off, 64);
    }

    if (tid < 32) {
      const int m = tid;
      // exact diagonal part d^8192
      c32 dL = dd;
      #pragma unroll
      for (int i2 = 0; i2 < 13; i2++) dL = cmul(dL, dL);
      // total S: 2 halves + z=-1 node (q real, half weight)
      c32 S;
      S.x = Sws[h*128 + 2*m]     + Sws[h*128 + 64 + 2*m];
      S.y = Sws[h*128 + 2*m + 1] + Sws[h*128 + 64 + 2*m + 1];
      float qn = -aterm * frcp(1.0f + bterm) * 0.5f;
      S.x += qn * 2.0f * glxn;
      S.y += qn * 2.0f * glyn;
      // C~ = C - (C dL - u S / 8192)
      c32 y = cmul(Cf, dL);
      c32 uS = cmul(u, S);
      y.x -= uS.x * (1.0f/8192.0f);
      y.y -= uS.y * (1.0f/8192.0f);
      c32 Ct = csub(Cf, y);
      // stage-B tables (poly-Cauchy constants), all dt-scaled
      c32 Bc = make_float2(Bin[(h*NN+m)*2], Bin[(h*NN+m)*2+1]);
      c32 Qc = cconjf(Pf);    // lane<32: Pf unconjugated
      c32 v00 = cmul(Bc, Ct), v01 = cmul(Bc, Qc), v10 = cmul(Pf, Ct), v11 = cmul(Pf, Qc);
      float wx = wr*dt, wy = wi*dt;
      float aw = fmaf(wx, wx, wy*wy);
      float tnw = -(wx + wx);
      float td = dt + dt;
      float a00 = td*v00.x, b00 = td*(v00.x*wx + v00.y*wy);
      float a01 = td*v01.x, b01 = td*(v01.x*wx + v01.y*wy);
      float a10 = td*v10.x, b10 = td*(v10.x*wx + v10.y*wy);
      float a11 = td*v11.x, b11 = td*(v11.x*wx + v11.y*wy);
      cs1_s[m] = make_float4(aw, tnw, a00, b00);
      cs2_s[m] = make_float4(a01, b01, a10, b10);
      cs3_s[m] = make_float2(a11, b11);
      // Nyquist X[4096] = sum Re(v00*dt)
      float s00 = v00.x * dt;
      #pragma unroll
      for (int off = 16; off >= 1; off >>= 1) s00 += __shfl_xor(s00, off, 64);
      if (m == 0) Xs[MF] = make_float2(s00, 0.0f);
    }
  }
  __syncthreads();

  // ---- poly Cauchy at z_j = 2i tan(pi j/L), 4 nodes/thread ----
  {
    float Tq[4], t2[4], t2sq[4];
    c32 a00[4], a01[4], a10[4], a11[4];
    #pragma unroll
    for (int q = 0; q < 4; q++) {
      int j = tid + (q << 10);
      float rev = (float)j * (1.0f/16384.0f);
      float sn = __builtin_amdgcn_sinf(rev);
      float cs = __builtin_amdgcn_cosf(rev);
      float T = sn * frcp(cs);
      Tq[q] = T; t2[q] = 2.0f*T; t2sq[q] = t2[q]*t2[q];
      a00[q] = make_float2(0,0); a01[q] = make_float2(0,0);
      a10[q] = make_float2(0,0); a11[q] = make_float2(0,0);
    }
    #pragma unroll 2
    for (int n = 0; n < NN; n++) {
      float4 C1 = cs1_s[n];   // aw, tnw, a00, b00
      float4 C2 = cs2_s[n];   // a01, b01, a10, b10
      c32   C3 = cs3_s[n];    // a11, b11
      #pragma unroll
      for (int q = 0; q < 4; q++) {
        float wvx = C1.x - t2sq[q];
        float wvy = C1.y * t2[q];
        float r = frcp(fmaf(wvx, wvx, wvy*wvy));
        float iwx = wvx*r;
        float iwy = -wvy*r;
        // acc += (-beta + i alpha t2) * iw, per vector
        float at;
        at = C1.z*t2[q];
        a00[q].x = fmaf(-C1.w, iwx, fmaf(-at, iwy, a00[q].x));
        a00[q].y = fmaf(-C1.w, iwy, fmaf( at, iwx, a00[q].y));
        at = C2.x*t2[q];
        a01[q].x = fmaf(-C2.y, iwx, fmaf(-at, iwy, a01[q].x));
        a01[q].y = fmaf(-C2.y, iwy, fmaf( at, iwx, a01[q].y));
        at = C2.z*t2[q];
        a10[q].x = fmaf(-C2.w, iwx, fmaf(-at, iwy, a10[q].x));
        a10[q].y = fmaf(-C2.w, iwy, fmaf( at, iwx, a10[q].y));
        at = C3.x*t2[q];
        a11[q].x = fmaf(-C3.y, iwx, fmaf(-at, iwy, a11[q].x));
        a11[q].y = fmaf(-C3.y, iwy, fmaf( at, iwx, a11[q].y));
      }
    }
    #pragma unroll
    for (int q = 0; q < 4; q++) {
      float denx = 1.0f + a11[q].x, deny = a11[q].y;
      float idn = frcp(fmaf(denx, denx, deny*deny));
      c32 invden = make_float2(denx*idn, -deny*idn);
      c32 kf = csub(a00[q], cmul(cmul(a01[q], a10[q]), invden));
      float T = Tq[q];
      Xs[tid + (q << 10)] = make_float2(kf.x - T*kf.y, kf.y + T*kf.x);  // *(1+iT)
    }
  }
  __syncthreads();

  // ---- real-irfft packing: Z[k] = (E[k] + i*O[k]) / MF ----
  const float invM = 1.0f / (float)MF;
  #pragma unroll
  for (int qq = 0; qq < 4; qq++) {
    int k = tid + (qq << 10);
    c32 Xk = Xs[k];
    c32 Xm = Xs[MF - k];
    float Ex = 0.5f*(Xk.x + Xm.x), Ey = 0.5f*(Xk.y - Xm.y);
    float Ox = 0.5f*(Xk.x - Xm.x), Oy = 0.5f*(Xk.y + Xm.y);
    float rev = (float)k * (1.0f/8192.0f);
    float cs = __builtin_amdgcn_cosf(rev);
    float sn = __builtin_amdgcn_sinf(rev);
    float Orx = Ox*cs - Oy*sn;
    float Ory = Ox*sn + Oy*cs;
    Zs[k] = make_float2((Ex - Ory)*invM, (Ey + Orx)*invM);
  }
  __syncthreads();

  // ---- 6-stage radix-4 Stockham inverse FFT (twiddle sign +) ----
  c32* srcf = Zs;
  c32* dstf = Xs;
  int sstride = 1;
  #pragma unroll
  for (int st = 0; st < 6; st++) {
    int jm = tid & ~(sstride - 1);
    float rev = (float)jm * (1.0f/4096.0f);
    float sn = __builtin_amdgcn_sinf(rev);
    float cs = __builtin_amdgcn_cosf(rev);
    c32 w1 = make_float2(cs, sn);
    c32 w2 = cmul(w1, w1);
    c32 w3 = cmul(w2, w1);
    c32 a = srcf[tid];
    c32 b = srcf[tid + 1024];
    c32 c = srcf[tid + 2048];
    c32 d = srcf[tid + 3072];
    c32 apc = cadd(a, c), amc = csub(a, c);
    c32 bpd = cadd(b, d), bmd = csub(b, d);
    int wb = tid + 3*jm;
    dstf[wb] = cadd(apc, bpd);
    dstf[wb + sstride]   = cmul(w1, make_float2(amc.x - bmd.y, amc.y + bmd.x));
    dstf[wb + 2*sstride] = cmul(w2, csub(apc, bpd));
    dstf[wb + 3*sstride] = cmul(w3, make_float2(amc.x + bmd.y, amc.y - bmd.x));
    __syncthreads();
    c32* t = srcf; srcf = dstf; dstf = t;
    sstride <<= 2;
  }

  // even stage count -> result in Zs (= srcf); z[m] = (x[2m], x[2m+1])
  {
    float4* o4 = (float4*)(out + (size_t)h*MF);
    const float4* s4 = (const float4*)srcf;
    o4[tid] = s4[tid];
    o4[tid + 1024] = s4[tid + 1024];
  }
}

extern "C" void kernel_launch(void* const* d_in, const int* in_sizes, int n_in,
                              void* d_out, int out_size, void* d_ws, size_t ws_size,
                              hipStream_t stream) {
  const float* log_dt = (const float*)d_in[0];
  const float* invwr  = (const float*)d_in[1];
  const float* wimag  = (const float*)d_in[2];
  const float* P      = (const float*)d_in[3];
  const float* B      = (const float*)d_in[4];
  const float* C      = (const float*)d_in[5];
  float* Sws = (float*)d_ws;                 // 512 blocks * 64 floats = 128 KB
  c32*   out = (c32*)d_out;                  // (H,8192) fp32 = (H,4096) c32
  (void)in_sizes; (void)n_in; (void)out_size; (void)ws_size;

  ssk_S<<<2*HH, 512, 0, stream>>>(log_dt, invwr, wimag, P, C, Sws);
  ssk_B<<<HH, 1024, 0, stream>>>(log_dt, invwr, wimag, P, B, C, Sws, out);
}